// Round 11
// baseline (682.599 us; speedup 1.0000x reference)
//
#include <hip/hip_runtime.h>
#include <float.h>
#include <stdint.h>

#define D_DIM 512

typedef __attribute__((ext_vector_type(8))) short bf16x8;
typedef __attribute__((ext_vector_type(4))) float f32x4;

// async global->LDS, 16B per lane (linear LDS dest: wave base + lane*16)
#define GLD_LDS16(g, l)                                              \
    __builtin_amdgcn_global_load_lds(                                \
        (const __attribute__((address_space(1))) void*)(g),          \
        (__attribute__((address_space(3))) void*)(l), 16, 0, 0)

// round-half-up f32->bf16, pack two into one u32
__device__ __forceinline__ uint32_t pk_bf16(float a, float b) {
    uint32_t ua = __builtin_bit_cast(uint32_t, a) + 0x8000u;
    uint32_t ub = __builtin_bit_cast(uint32_t, b) + 0x8000u;
    return (ua >> 16) | (ub & 0xFFFF0000u);
}

// sorted-desc top-4 insert, static indices only
#define INS4(val, idx, tv, ti)                                        \
    if ((val) > tv[3]) {                                              \
        int p_ = 3;                                                   \
        if ((val) > tv[2]) { tv[3] = tv[2]; ti[3] = ti[2]; p_ = 2; }  \
        if ((val) > tv[1]) { tv[2] = tv[1]; ti[2] = ti[1]; p_ = 1; }  \
        if ((val) > tv[0]) { tv[1] = tv[0]; ti[1] = ti[0]; p_ = 0; }  \
        tv[p_] = (val); ti[p_] = (idx);                               \
    }

// ---------------------------------------------------------------------------
// Per-row: r[row] = 1/max(||X[row]||,eps); Xb[row,:] = bf16(X[row,:] * r).
// ---------------------------------------------------------------------------
__global__ __launch_bounds__(256) void convert_norm_kernel(
        const float* __restrict__ X, unsigned short* __restrict__ Xb,
        float* __restrict__ r, int R) {
    int row = blockIdx.x * 4 + (threadIdx.x >> 6);
    if (row >= R) return;
    int lane = threadIdx.x & 63;
    const float* x = X + (size_t)row * D_DIM + lane * 8;
    float4 f0 = *(const float4*)(x);
    float4 f1 = *(const float4*)(x + 4);
    float s = f0.x*f0.x + f0.y*f0.y + f0.z*f0.z + f0.w*f0.w
            + f1.x*f1.x + f1.y*f1.y + f1.z*f1.z + f1.w*f1.w;
#pragma unroll
    for (int off = 32; off; off >>= 1) s += __shfl_xor(s, off);
    float rv = 1.0f / fmaxf(sqrtf(s), 1e-12f);
    if (lane == 0) r[row] = rv;
    uint4 w;
    w.x = pk_bf16(f0.x * rv, f0.y * rv);
    w.y = pk_bf16(f0.z * rv, f0.w * rv);
    w.z = pk_bf16(f1.x * rv, f1.y * rv);
    w.w = pk_bf16(f1.z * rv, f1.w * rv);
    *(uint4*)(Xb + (size_t)row * D_DIM + lane * 8) = w;
}

// ---------------------------------------------------------------------------
// 256x256 8-wave bf16 GEMM, counted-vmcnt 4-deep pipeline (r10/r11):
// BK=32 subtiles (16 total), 4 LDS buffers (4 x 32KB = 128KB dynamic).
// Per iter s: {12 ds_read of subtile s || issue subtile s+3 (4 gload_lds)}
//  -> vmcnt(8) (certifies s+1; 8 loads stay in flight, NEVER drains)
//  -> barrier -> lgkmcnt(0)+sched_barrier -> 32 MFMA (setprio) -> barrier.
// Cert: each wave's vmcnt covers its own stores; barrier -> all-wave.
// Reuse: buf[s&3] reads finish before s's closing barrier; overwrite is
// issued at iter s+1 (after that barrier) -> race-free.
// Chunk-XOR swizzle (c ^ row&3) on global source + ds_read (both sides).
// Fused epilogue: transpose quadrant -> T[128][132]; NONTEMPORAL f32x4
// sim stores (nothing re-reads sim); gated scan -> per-thread top-4;
// shfl-merge; top-4/row/256-tile -> part.
// ---------------------------------------------------------------------------
__global__ __launch_bounds__(512, 2) void gemm256_fused(
        const unsigned short* __restrict__ Zb,
        const unsigned short* __restrict__ Pb,
        float* __restrict__ sim, uint2* __restrict__ part, int Pn) {
    extern __shared__ __align__(16) unsigned char SH[];
    uint4* S = (uint4*)SH;   // buf q: q*2048 + (A: 0..1023 | B: 1024..2047)

    int bi = blockIdx.x;
    int mb, nb;
    if (gridDim.x == 4096) {             // XCD chunk map (B=8192, P=32768)
        int xcd = bi & 7, r = bi >> 3;
        mb = xcd * 4 + (r & 3);          // 0..31
        nb = r >> 2;                     // 0..127
    } else {
        int nt = Pn >> 8;
        nb = bi % nt; mb = bi / nt;
    }
    const int bm = mb << 8, bn = nb << 8;

    const int tid = threadIdx.x;
    const int lane = tid & 63;
    const int wid = tid >> 6;
    const int wr = wid >> 2;             // 0..1
    const int wc = wid & 3;              // 0..3
    const int ln15 = lane & 15, hi = lane >> 4;

    // ---- staging addressing: per thread 2 chunks for A and 2 for B ----
    const int f0 = tid, f1 = 512 + tid;
    const int r0 = f0 >> 2, r1 = f1 >> 2;              // 0..127 / 128..255
    const int cg0 = (f0 & 3) ^ (r0 & 3);
    const int cg1 = (f1 & 3) ^ (r1 & 3);

    const unsigned short* pA0 = Zb + (size_t)(bm + r0) * D_DIM + cg0 * 8;
    const unsigned short* pA1 = Zb + (size_t)(bm + r1) * D_DIM + cg1 * 8;
    const unsigned short* pB0 = Pb + (size_t)(bn + r0) * D_DIM + cg0 * 8;
    const unsigned short* pB1 = Pb + (size_t)(bn + r1) * D_DIM + cg1 * 8;

#define ISSUE(qb)                                                    \
    do {                                                             \
        GLD_LDS16(pA0, &S[(qb) * 2048 + f0]);                        \
        GLD_LDS16(pA1, &S[(qb) * 2048 + f1]);                        \
        GLD_LDS16(pB0, &S[(qb) * 2048 + 1024 + f0]);                 \
        GLD_LDS16(pB1, &S[(qb) * 2048 + 1024 + f1]);                 \
        pA0 += 32; pA1 += 32; pB0 += 32; pB1 += 32;                  \
    } while (0)

    // ---- fragment read offsets (uint4 index within a buffer) ----
    const int sw = hi ^ (ln15 & 3);      // row&3 == ln15&3 for all frags
    int aOff[8], bOff[4];
#pragma unroll
    for (int m = 0; m < 8; ++m) aOff[m] = (wr * 128 + m * 16 + ln15) * 4 + sw;
#pragma unroll
    for (int n = 0; n < 4; ++n) bOff[n] = 1024 + (wc * 64 + n * 16 + ln15) * 4 + sw;

    f32x4 acc[8][4] = {};

    // ---- prologue: stage subtiles 0,1,2; certify 0; sync ----
    ISSUE(0); ISSUE(1); ISSUE(2);
    asm volatile("s_waitcnt vmcnt(8)" ::: "memory");
    __builtin_amdgcn_s_barrier();

#pragma unroll 1
    for (int s = 0; s < 16; ++s) {
        const int qb = s & 3;
        // reads of subtile s (certified at iter s-1 / prologue)
        bf16x8 av[8], bv[4];
#pragma unroll
        for (int mi = 0; mi < 8; ++mi)
            av[mi] = __builtin_bit_cast(bf16x8, S[qb * 2048 + aOff[mi]]);
#pragma unroll
        for (int ni = 0; ni < 4; ++ni)
            bv[ni] = __builtin_bit_cast(bf16x8, S[qb * 2048 + bOff[ni]]);
        // issue subtile s+3; counted wait certifies s+1 (never drain to 0)
        if (s < 13) {
            ISSUE((s + 3) & 3);
            asm volatile("s_waitcnt vmcnt(8)" ::: "memory");
        } else if (s == 13) {
            asm volatile("s_waitcnt vmcnt(4)" ::: "memory");
        } else {
            asm volatile("s_waitcnt vmcnt(0)" ::: "memory");
        }
        __builtin_amdgcn_s_barrier();
        asm volatile("s_waitcnt lgkmcnt(0)" ::: "memory");
        __builtin_amdgcn_sched_barrier(0);
        __builtin_amdgcn_s_setprio(1);
#pragma unroll
        for (int mi = 0; mi < 8; ++mi)
#pragma unroll
            for (int ni = 0; ni < 4; ++ni)
                acc[mi][ni] = __builtin_amdgcn_mfma_f32_16x16x32_bf16(
                    av[mi], bv[ni], acc[mi][ni], 0, 0, 0);
        __builtin_amdgcn_s_setprio(0);
        __builtin_amdgcn_sched_barrier(0);
        __builtin_amdgcn_s_barrier();
    }
#undef ISSUE

    // ---- fused epilogue: transpose -> T, nontemporal sim store, top-4 ----
    float* T = (float*)SH;               // [128 cols][132] f32 = 67584 B
    const int NB = Pn >> 8;
    const int r = tid >> 2;              // 0..127
    const int g = tid & 3;               // col group (4 lanes per row)
#pragma unroll 1
    for (int hf = 0; hf < 2; ++hf) {
        float tv[4]; int ti[4];
#pragma unroll
        for (int k = 0; k < 4; ++k) { tv[k] = -FLT_MAX; ti[k] = 0x7FFFFFFF; }
#pragma unroll 1
        for (int ch = 0; ch < 2; ++ch) {
            __syncthreads();             // T free
            if (wr == hf && (wc >> 1) == ch) {
#pragma unroll
                for (int m = 0; m < 8; ++m)
#pragma unroll
                    for (int n = 0; n < 4; ++n)
                        *(f32x4*)&T[((wc & 1) * 64 + n * 16 + ln15) * 132
                                    + m * 16 + hi * 4] = acc[m][n];
            }
            __syncthreads();
            const int colBase = bn + ch * 128;
            float* srow = sim + (size_t)(bm + hf * 128 + r) * Pn + colBase;
#pragma unroll
            for (int j = 0; j < 8; ++j) {
                const int c0 = j * 16 + g * 4;
                float e0 = T[(c0 + 0) * 132 + r];
                float e1 = T[(c0 + 1) * 132 + r];
                float e2 = T[(c0 + 2) * 132 + r];
                float e3 = T[(c0 + 3) * 132 + r];
                f32x4 o; o[0] = e0; o[1] = e1; o[2] = e2; o[3] = e3;
                __builtin_nontemporal_store(o, (f32x4*)&srow[c0]);
                float mg = fmaxf(fmaxf(e0, e1), fmaxf(e2, e3));
                if (mg > tv[3]) {
                    INS4(e0, colBase + c0 + 0, tv, ti);
                    INS4(e1, colBase + c0 + 1, tv, ti);
                    INS4(e2, colBase + c0 + 2, tv, ti);
                    INS4(e3, colBase + c0 + 3, tv, ti);
                }
            }
        }
        // merge top-4 across the 4-lane col groups (lanes 4r..4r+3)
#pragma unroll
        for (int st = 1; st <= 2; st <<= 1) {
            float ov0 = __shfl_xor(tv[0], st), ov1 = __shfl_xor(tv[1], st);
            float ov2 = __shfl_xor(tv[2], st), ov3 = __shfl_xor(tv[3], st);
            int oi0 = __shfl_xor(ti[0], st), oi1 = __shfl_xor(ti[1], st);
            int oi2 = __shfl_xor(ti[2], st), oi3 = __shfl_xor(ti[3], st);
            INS4(ov0, oi0, tv, ti);
            INS4(ov1, oi1, tv, ti);
            INS4(ov2, oi2, tv, ti);
            INS4(ov3, oi3, tv, ti);
        }
        if (g == 0) {
            size_t o = ((size_t)(bm + hf * 128 + r) * NB + nb) * 4;
#pragma unroll
            for (int k = 0; k < 4; ++k)
                part[o + k] =
                    make_uint2(__builtin_bit_cast(uint32_t, tv[k]), (uint32_t)ti[k]);
        }
    }
}

// ---------------------------------------------------------------------------
// Reduce partial candidates (NB*4 per row) -> noisy top-8 -> exact f32
// rerank -> top-3. One wave per row.
// ---------------------------------------------------------------------------
__global__ __launch_bounds__(256) void topk_reduce(const uint2* __restrict__ part,
        const float* __restrict__ Z, const float* __restrict__ Pm,
        const float* __restrict__ rz, const float* __restrict__ rp,
        float* __restrict__ oidx, float* __restrict__ oval, int Pn, int NB) {
    int row = blockIdx.x * 4 + (threadIdx.x >> 6);
    int lane = threadIdx.x & 63;
    const uint2* pr = part + (size_t)row * NB * 4;

    float v[8]; int ix[8];
#pragma unroll
    for (int j = 0; j < 8; ++j) { v[j] = -FLT_MAX; ix[j] = -1; }

    const int total = NB * 4;
    for (int c = lane; c < total; c += 64) {
        uint2 u = pr[c];
        float val = __builtin_bit_cast(float, u.x);
        if (val > v[7]) {
            int idx = (int)u.y;
            int pos = 7;
#pragma unroll
            for (int j = 6; j >= 0; --j) {
                if (val > v[j]) { v[j+1] = v[j]; ix[j+1] = ix[j]; pos = j; }
            }
            v[pos] = val; ix[pos] = idx;
        }
    }

    int cand[8];
#pragma unroll
    for (int k = 0; k < 8; ++k) {
        float bv = v[0]; int bi2 = ix[0];
#pragma unroll
        for (int off = 32; off; off >>= 1) {
            float ov = __shfl_xor(bv, off);
            int oi = __shfl_xor(bi2, off);
            if (ov > bv || (ov == bv && oi >= 0 && (unsigned)oi < (unsigned)bi2)) {
                bv = ov; bi2 = oi;
            }
        }
        cand[k] = bi2;
        if (bi2 == ix[0]) {
#pragma unroll
            for (int j = 0; j < 7; ++j) { v[j] = v[j+1]; ix[j] = ix[j+1]; }
            v[7] = -FLT_MAX; ix[7] = -1;
        }
    }

    // exact f32 recompute of the 8 candidate similarities
    float zv[8];
    const float* zrow = Z + (size_t)row * D_DIM + lane * 8;
#pragma unroll
    for (int j = 0; j < 8; ++j) zv[j] = zrow[j];
    float rzv = rz[row];

    float ex[8];
#pragma unroll
    for (int c = 0; c < 8; ++c) {
        int idx = cand[c];
        const float* prow = Pm + (size_t)idx * D_DIM + lane * 8;
        float s = 0.f;
#pragma unroll
        for (int j = 0; j < 8; ++j) s += zv[j] * prow[j];
#pragma unroll
        for (int off = 32; off; off >>= 1) s += __shfl_xor(s, off);
        ex[c] = s * rzv * rp[idx];
    }

    bool used[8] = {};
#pragma unroll
    for (int k = 0; k < 3; ++k) {
        float bv = -FLT_MAX; int bi2 = Pn; int bc = 0;
#pragma unroll
        for (int c = 0; c < 8; ++c) {
            if (!used[c] && (ex[c] > bv || (ex[c] == bv && cand[c] < bi2))) {
                bv = ex[c]; bi2 = cand[c]; bc = c;
            }
        }
        used[bc] = true;
        if (lane == 0) {
            oidx[(size_t)row * 3 + k] = (float)bi2;
            oval[(size_t)row * 3 + k] = bv;
        }
    }
}

// ---------------------------------------------------------------------------
// Fallback: 128x128 2-phase kernel (attr failure / smaller ws).
// ---------------------------------------------------------------------------
template <bool FUSE>
__global__ __launch_bounds__(256, 4) void gemm_lds_bf16(
        const unsigned short* __restrict__ Zb,
        const unsigned short* __restrict__ Pb,
        float* __restrict__ sim, uint2* __restrict__ part, int Pn) {
    __shared__ __align__(16) unsigned char SHs[32768];
    uint4* S = (uint4*)SHs;

    int bi = blockIdx.x;
    int mb, nb;
    if (gridDim.x == 16384) {
        int xcd = bi & 7;
        int r = bi >> 3;
        mb = xcd * 8 + (r & 7);
        nb = r >> 3;
    } else {
        nb = bi % (Pn / 128);
        mb = bi / (Pn / 128);
    }
    const int bm = mb * 128, bn = nb * 128;

    const int tid = threadIdx.x;
    const int lane = tid & 63;
    const int wid = tid >> 6;
    const int wr = wid >> 1, wc = wid & 1;
    const int ln15 = lane & 15, hi = lane >> 4;

    const unsigned short* gA[2];
    const unsigned short* gB[2];
    int ldsIdx[2];
#pragma unroll
    for (int q = 0; q < 2; ++q) {
        int flat = q * 256 + tid;
        int row = flat >> 2;
        int c = flat & 3;
        int cg = c ^ (row & 3);
        gA[q] = Zb + (size_t)(bm + row) * D_DIM + cg * 8;
        gB[q] = Pb + (size_t)(bn + row) * D_DIM + cg * 8;
        ldsIdx[q] = flat;
    }

    f32x4 acc[4][4] = {};

#pragma unroll
    for (int q = 0; q < 2; ++q) {
        GLD_LDS16(gA[q], &S[ldsIdx[q]]);
        GLD_LDS16(gB[q], &S[512 + ldsIdx[q]]);
        gA[q] += 32;
        gB[q] += 32;
    }

    int cur = 0;
#pragma unroll 1
    for (int s8 = 0; s8 < 16; ++s8) {
        const int nxt = cur ^ 1;
        if (s8 < 15) {
#pragma unroll
            for (int q = 0; q < 2; ++q) {
                GLD_LDS16(gA[q], &S[nxt * 1024 + ldsIdx[q]]);
                GLD_LDS16(gB[q], &S[nxt * 1024 + 512 + ldsIdx[q]]);
                gA[q] += 32;
                gB[q] += 32;
            }
            asm volatile("s_waitcnt vmcnt(4)" ::: "memory");
        } else {
            asm volatile("s_waitcnt vmcnt(0)" ::: "memory");
        }
        __builtin_amdgcn_s_barrier();
        __builtin_amdgcn_sched_barrier(0);

        const int sb = cur * 1024;
        __builtin_amdgcn_s_setprio(1);
        bf16x8 av[4], bv[4];
#pragma unroll
        for (int t = 0; t < 4; ++t) {
            int arow = wr * 64 + t * 16 + ln15;
            av[t] = __builtin_bit_cast(bf16x8,
                    S[sb + arow * 4 + (hi ^ (arow & 3))]);
            int brow = wc * 64 + t * 16 + ln15;
            bv[t] = __builtin_bit_cast(bf16x8,
                    S[sb + 512 + brow * 4 + (hi ^ (brow & 3))]);
        }
#pragma unroll
        for (int i = 0; i < 4; ++i)
#pragma unroll
            for (int j = 0; j < 4; ++j)
                acc[i][j] = __builtin_amdgcn_mfma_f32_16x16x32_bf16(
                    av[i], bv[j], acc[i][j], 0, 0, 0);
        __builtin_amdgcn_s_setprio(0);
        __builtin_amdgcn_sched_barrier(0);
        __builtin_amdgcn_s_barrier();
        cur = nxt;
    }

#pragma unroll
    for (int i = 0; i < 4; ++i) {
#pragma unroll
        for (int rr = 0; rr < 4; ++rr) {
            int row = bm + wr * 64 + i * 16 + hi * 4 + rr;
#pragma unroll
            for (int j = 0; j < 4; ++j) {
                int col = bn + wc * 64 + j * 16 + ln15;
                sim[(size_t)row * Pn + col] = acc[i][j][rr];
            }
        }
    }

    if constexpr (FUSE) {
        float* T = (float*)SHs;
        uint2* M = (uint2*)(SHs + 17408);
        const int NB = Pn >> 7;
        const int r = tid & 63;
        const int q = tid >> 6;
#pragma unroll 1
        for (int hf = 0; hf < 2; ++hf) {
            float rv[4]; int ri[4];
#pragma unroll
            for (int k = 0; k < 4; ++k) { rv[k] = -FLT_MAX; ri[k] = 0x7FFFFFFF; }
#pragma unroll 1
            for (int ch = 0; ch < 2; ++ch) {
                __syncthreads();
                if (wr == hf && wc == ch) {
#pragma unroll
                    for (int i = 0; i < 4; ++i)
#pragma unroll
                        for (int j = 0; j < 4; ++j)
                            *(f32x4*)&T[(j * 16 + ln15) * 68 + i * 16 + hi * 4]
                                = acc[i][j];
                }
                __syncthreads();
                float tv[4]; int ti[4];
#pragma unroll
                for (int k = 0; k < 4; ++k) { tv[k] = -FLT_MAX; ti[k] = 0x7FFFFFFF; }
#pragma unroll
                for (int c4 = 0; c4 < 16; c4 += 4) {
                    float e0 = T[(q * 16 + c4 + 0) * 68 + r];
                    float e1 = T[(q * 16 + c4 + 1) * 68 + r];
                    float e2 = T[(q * 16 + c4 + 2) * 68 + r];
                    float e3 = T[(q * 16 + c4 + 3) * 68 + r];
                    float mg = fmaxf(fmaxf(e0, e1), fmaxf(e2, e3));
                    if (mg > tv[3]) {
                        int cb = bn + ch * 64 + q * 16 + c4;
                        INS4(e0, cb + 0, tv, ti);
                        INS4(e1, cb + 1, tv, ti);
                        INS4(e2, cb + 2, tv, ti);
                        INS4(e3, cb + 3, tv, ti);
                    }
                }
#pragma unroll
                for (int k = 0; k < 4; ++k)
                    M[q * 256 + k * 64 + r] =
                        make_uint2(__builtin_bit_cast(uint32_t, tv[k]), (uint32_t)ti[k]);
                __syncthreads();
                if (tid < 64) {
#pragma unroll
                    for (int qq = 0; qq < 4; ++qq)
#pragma unroll
                        for (int k = 0; k < 4; ++k) {
                            uint2 u = M[qq * 256 + k * 64 + tid];
                            float val = __builtin_bit_cast(float, u.x);
                            INS4(val, (int)u.y, rv, ri);
                        }
                }
            }
            if (tid < 64) {
                size_t o = ((size_t)(bm + hf * 64 + tid) * NB + nb) * 4;
#pragma unroll
                for (int k = 0; k < 4; ++k)
                    part[o + k] =
                        make_uint2(__builtin_bit_cast(uint32_t, rv[k]), (uint32_t)ri[k]);
            }
        }
    }
}

// ---------------------------------------------------------------------------
// Deep fallbacks: f32-input GEMM + full-sim topk (tiny ws).
// ---------------------------------------------------------------------------
__global__ __launch_bounds__(256) void rnorm_kernel(const float* __restrict__ X,
                                                    float* __restrict__ r, int R) {
    int row = blockIdx.x * 4 + (threadIdx.x >> 6);
    if (row >= R) return;
    int lane = threadIdx.x & 63;
    const float* x = X + (size_t)row * D_DIM;
    float s = 0.f;
#pragma unroll
    for (int t = 0; t < 2; ++t) {
        float4 v = *(const float4*)(x + (t * 64 + lane) * 4);
        s += v.x * v.x + v.y * v.y + v.z * v.z + v.w * v.w;
    }
#pragma unroll
    for (int off = 32; off; off >>= 1) s += __shfl_xor(s, off);
    if (lane == 0) r[row] = 1.0f / fmaxf(sqrtf(s), 1e-12f);
}

__global__ __launch_bounds__(256, 2) void gemm_bf16_sim(const float* __restrict__ Z,
        const float* __restrict__ Pm, const float* __restrict__ rz,
        const float* __restrict__ rp, float* __restrict__ sim, int Pn) {
    __shared__ uint4 As16[1024];
    __shared__ uint4 Bs16[1024];
    int bi = blockIdx.x;
    int nb = bi % (Pn / 128);
    int mb = bi / (Pn / 128);
    const int bm = mb * 128, bn = nb * 128;
    const int tid = threadIdx.x;
    const int srow = tid >> 1;
    const int half = tid & 1;
    const float* aP = Z  + (size_t)(bm + srow) * D_DIM + half * 32;
    const float* bP = Pm + (size_t)(bn + srow) * D_DIM + half * 32;
    const int lane = tid & 63;
    const int wid = tid >> 6;
    const int wr = wid >> 1, wc = wid & 1;
    const int ln15 = lane & 15, hi = lane >> 4;
    f32x4 acc[4][4] = {};
    float4 f[8], g[8];
#pragma unroll
    for (int q = 0; q < 8; ++q) {
        f[q] = *(const float4*)(aP + q * 4);
        g[q] = *(const float4*)(bP + q * 4);
    }
#pragma unroll 1
    for (int s = 0; s < 8; ++s) {
#pragma unroll
        for (int q8 = 0; q8 < 4; ++q8) {
            uint4 wa, wb;
            wa.x = pk_bf16(f[2*q8].x,   f[2*q8].y);
            wa.y = pk_bf16(f[2*q8].z,   f[2*q8].w);
            wa.z = pk_bf16(f[2*q8+1].x, f[2*q8+1].y);
            wa.w = pk_bf16(f[2*q8+1].z, f[2*q8+1].w);
            wb.x = pk_bf16(g[2*q8].x,   g[2*q8].y);
            wb.y = pk_bf16(g[2*q8].z,   g[2*q8].w);
            wb.z = pk_bf16(g[2*q8+1].x, g[2*q8+1].y);
            wb.w = pk_bf16(g[2*q8+1].z, g[2*q8+1].w);
            int colByte = half * 64 + q8 * 16;
            int idx = srow * 8 + ((colByte ^ ((srow & 7) << 4)) >> 4);
            As16[idx] = wa;
            Bs16[idx] = wb;
        }
        __syncthreads();
        if (s < 7) {
            int k0 = (s + 1) * 64;
#pragma unroll
            for (int q = 0; q < 8; ++q) {
                f[q] = *(const float4*)(aP + k0 + q * 4);
                g[q] = *(const float4*)(bP + k0 + q * 4);
            }
        }
#pragma unroll
        for (int kk = 0; kk < 2; ++kk) {
            bf16x8 av[4], bv[4];
            const int cb = kk * 64 + hi * 16;
#pragma unroll
            for (int t = 0; t < 4; ++t) {
                int arow = wr * 64 + t * 16 + ln15;
                av[t] = __builtin_bit_cast(bf16x8,
                        As16[arow * 8 + ((cb ^ ((arow & 7) << 4)) >> 4)]);
                int brow = wc * 64 + t * 16 + ln15;
                bv[t] = __builtin_bit_cast(bf16x8,
                        Bs16[brow * 8 + ((cb ^ ((brow & 7) << 4)) >> 4)]);
            }
#pragma unroll
            for (int i = 0; i < 4; ++i)
#pragma unroll
                for (int j = 0; j < 4; ++j)
                    acc[i][j] = __builtin_amdgcn_mfma_f32_16x16x32_bf16(
                        av[i], bv[j], acc[i][j], 0, 0, 0);
        }
        __syncthreads();
    }
    float rpv[4];
#pragma unroll
    for (int j = 0; j < 4; ++j) rpv[j] = rp[bn + wc * 64 + j * 16 + ln15];
#pragma unroll
    for (int i = 0; i < 4; ++i) {
#pragma unroll
        for (int rr = 0; rr < 4; ++rr) {
            int row = bm + wr * 64 + i * 16 + hi * 4 + rr;
            float rzv = rz[row];
#pragma unroll
            for (int j = 0; j < 4; ++j) {
                int col = bn + wc * 64 + j * 16 + ln15;
                sim[(size_t)row * Pn + col] = acc[i][j][rr] * rzv * rpv[j];
            }
        }
    }
}

__global__ __launch_bounds__(256) void topk_refine(const float* __restrict__ sim,
        const float* __restrict__ Z, const float* __restrict__ Pm,
        const float* __restrict__ rz, const float* __restrict__ rp,
        float* __restrict__ oidx, float* __restrict__ oval, int Pn) {
    int row = blockIdx.x * 4 + (threadIdx.x >> 6);
    int lane = threadIdx.x & 63;
    const float* rptr = sim + (size_t)row * Pn;

    float v[8]; int ix[8];
#pragma unroll
    for (int j = 0; j < 8; ++j) { v[j] = -FLT_MAX; ix[j] = -1; }

    const int iters = Pn >> 8;
    for (int t = 0; t < iters; ++t) {
        int base = t * 256 + lane * 4;
        float4 q = *(const float4*)(rptr + base);
        float vals[4] = {q.x, q.y, q.z, q.w};
#pragma unroll
        for (int e = 0; e < 4; ++e) {
            float val = vals[e];
            if (val > v[7]) {
                int idx = base + e;
                int pos = 7;
#pragma unroll
                for (int j = 6; j >= 0; --j) {
                    if (val > v[j]) { v[j+1] = v[j]; ix[j+1] = ix[j]; pos = j; }
                }
                v[pos] = val; ix[pos] = idx;
            }
        }
    }

    int cand[8];
#pragma unroll
    for (int k = 0; k < 8; ++k) {
        float bv = v[0]; int bi2 = ix[0];
#pragma unroll
        for (int off = 32; off; off >>= 1) {
            float ov = __shfl_xor(bv, off);
            int oi = __shfl_xor(bi2, off);
            if (ov > bv || (ov == bv && oi >= 0 && (unsigned)oi < (unsigned)bi2)) {
                bv = ov; bi2 = oi;
            }
        }
        cand[k] = bi2;
        if (bi2 == ix[0]) {
#pragma unroll
            for (int j = 0; j < 7; ++j) { v[j] = v[j+1]; ix[j] = ix[j+1]; }
            v[7] = -FLT_MAX; ix[7] = -1;
        }
    }

    float zv[8];
    const float* zrow = Z + (size_t)row * D_DIM + lane * 8;
#pragma unroll
    for (int j = 0; j < 8; ++j) zv[j] = zrow[j];
    float rzv = rz[row];

    float ex[8];
#pragma unroll
    for (int c = 0; c < 8; ++c) {
        int idx = cand[c];
        const float* prow = Pm + (size_t)idx * D_DIM + lane * 8;
        float s = 0.f;
#pragma unroll
        for (int j = 0; j < 8; ++j) s += zv[j] * prow[j];
#pragma unroll
        for (int off = 32; off; off >>= 1) s += __shfl_xor(s, off);
        ex[c] = s * rzv * rp[idx];
    }

    bool used[8] = {};
#pragma unroll
    for (int k = 0; k < 3; ++k) {
        float bv = -FLT_MAX; int bi2 = Pn; int bc = 0;
#pragma unroll
        for (int c = 0; c < 8; ++c) {
            if (!used[c] && (ex[c] > bv || (ex[c] == bv && cand[c] < bi2))) {
                bv = ex[c]; bi2 = cand[c]; bc = c;
            }
        }
        used[bc] = true;
        if (lane == 0) {
            oidx[(size_t)row * 3 + k] = (float)bi2;
            oval[(size_t)row * 3 + k] = bv;
        }
    }
}

extern "C" void kernel_launch(void* const* d_in, const int* in_sizes, int n_in,
                              void* d_out, int out_size, void* d_ws, size_t ws_size,
                              hipStream_t stream) {
    const float* Z  = (const float*)d_in[0];   // [B, 512]
    const float* Pm = (const float*)d_in[1];   // [P, 512]
    const int B  = in_sizes[0] / D_DIM;        // 8192
    const int Pn = in_sizes[1] / D_DIM;        // 32768

    float* sim  = (float*)d_out;
    float* oidx = sim + (size_t)B * Pn;
    float* oval = oidx + (size_t)B * 3;

    float* rz = (float*)d_ws;
    float* rp = rz + B;
    unsigned short* Zb = (unsigned short*)(rp + Pn);
    unsigned short* Pb = Zb + (size_t)B * D_DIM;
    uint2* part = (uint2*)(Pb + (size_t)Pn * D_DIM);

    const size_t need_bf16 = (size_t)(B + Pn) * 4 + (size_t)(B + Pn) * D_DIM * 2;
    const size_t need256 = need_bf16 + (size_t)B * (Pn >> 8) * 4 * sizeof(uint2);
    const size_t need128 = need_bf16 + (size_t)B * (Pn >> 7) * 4 * sizeof(uint2);

    bool big = false;
    if ((B & 255) == 0 && (Pn & 255) == 0 && ws_size >= need256) {
        big = (hipFuncSetAttribute((const void*)gemm256_fused,
                   hipFuncAttributeMaxDynamicSharedMemorySize,
                   131072) == hipSuccess);
    }

    if (big) {
        convert_norm_kernel<<<B / 4, 256, 0, stream>>>(Z, Zb, rz, B);
        convert_norm_kernel<<<Pn / 4, 256, 0, stream>>>(Pm, Pb, rp, Pn);
        gemm256_fused<<<(B / 256) * (Pn / 256), 512, 131072, stream>>>(
            Zb, Pb, sim, part, Pn);
        topk_reduce<<<B / 4, 256, 0, stream>>>(part, Z, Pm, rz, rp,
                                               oidx, oval, Pn, Pn >> 8);
    } else if (ws_size >= need128) {
        convert_norm_kernel<<<B / 4, 256, 0, stream>>>(Z, Zb, rz, B);
        convert_norm_kernel<<<Pn / 4, 256, 0, stream>>>(Pm, Pb, rp, Pn);
        gemm_lds_bf16<true><<<(B / 128) * (Pn / 128), 256, 0, stream>>>(
            Zb, Pb, sim, part, Pn);
        topk_reduce<<<B / 4, 256, 0, stream>>>(part, Z, Pm, rz, rp,
                                               oidx, oval, Pn, Pn >> 7);
    } else if (ws_size >= need_bf16) {
        convert_norm_kernel<<<B / 4, 256, 0, stream>>>(Z, Zb, rz, B);
        convert_norm_kernel<<<Pn / 4, 256, 0, stream>>>(Pm, Pb, rp, Pn);
        gemm_lds_bf16<false><<<(B / 128) * (Pn / 128), 256, 0, stream>>>(
            Zb, Pb, sim, nullptr, Pn);
        topk_refine<<<B / 4, 256, 0, stream>>>(sim, Z, Pm, rz, rp, oidx, oval, Pn);
    } else {
        rnorm_kernel<<<B / 4, 256, 0, stream>>>(Z, rz, B);
        rnorm_kernel<<<Pn / 4, 256, 0, stream>>>(Pm, rp, Pn);
        gemm_bf16_sim<<<(B / 128) * (Pn / 128), 256, 0, stream>>>(
            Z, Pm, rz, rp, sim, Pn);
        topk_refine<<<B / 4, 256, 0, stream>>>(sim, Z, Pm, rz, rp, oidx, oval, Pn);
    }
}

// Round 12
// 674.994 us; speedup vs baseline: 1.0113x; 1.0113x over previous
//
#include <hip/hip_runtime.h>
#include <float.h>
#include <stdint.h>

#define D_DIM 512

typedef __attribute__((ext_vector_type(8))) short bf16x8;
typedef __attribute__((ext_vector_type(4))) float f32x4;

// async global->LDS, 16B per lane (linear LDS dest: wave base + lane*16)
#define GLD_LDS16(g, l)                                              \
    __builtin_amdgcn_global_load_lds(                                \
        (const __attribute__((address_space(1))) void*)(g),          \
        (__attribute__((address_space(3))) void*)(l), 16, 0, 0)

// round-half-up f32->bf16, pack two into one u32
__device__ __forceinline__ uint32_t pk_bf16(float a, float b) {
    uint32_t ua = __builtin_bit_cast(uint32_t, a) + 0x8000u;
    uint32_t ub = __builtin_bit_cast(uint32_t, b) + 0x8000u;
    return (ua >> 16) | (ub & 0xFFFF0000u);
}

// sorted-desc top-4 insert, static indices only
#define INS4(val, idx, tv, ti)                                        \
    if ((val) > tv[3]) {                                              \
        int p_ = 3;                                                   \
        if ((val) > tv[2]) { tv[3] = tv[2]; ti[3] = ti[2]; p_ = 2; }  \
        if ((val) > tv[1]) { tv[2] = tv[1]; ti[2] = ti[1]; p_ = 1; }  \
        if ((val) > tv[0]) { tv[1] = tv[0]; ti[1] = ti[0]; p_ = 0; }  \
        tv[p_] = (val); ti[p_] = (idx);                               \
    }

// ---------------------------------------------------------------------------
// Per-row: r[row] = 1/max(||X[row]||,eps); Xb[row,:] = bf16(X[row,:] * r).
// ---------------------------------------------------------------------------
__global__ __launch_bounds__(256) void convert_norm_kernel(
        const float* __restrict__ X, unsigned short* __restrict__ Xb,
        float* __restrict__ r, int R) {
    int row = blockIdx.x * 4 + (threadIdx.x >> 6);
    if (row >= R) return;
    int lane = threadIdx.x & 63;
    const float* x = X + (size_t)row * D_DIM + lane * 8;
    float4 f0 = *(const float4*)(x);
    float4 f1 = *(const float4*)(x + 4);
    float s = f0.x*f0.x + f0.y*f0.y + f0.z*f0.z + f0.w*f0.w
            + f1.x*f1.x + f1.y*f1.y + f1.z*f1.z + f1.w*f1.w;
#pragma unroll
    for (int off = 32; off; off >>= 1) s += __shfl_xor(s, off);
    float rv = 1.0f / fmaxf(sqrtf(s), 1e-12f);
    if (lane == 0) r[row] = rv;
    uint4 w;
    w.x = pk_bf16(f0.x * rv, f0.y * rv);
    w.y = pk_bf16(f0.z * rv, f0.w * rv);
    w.z = pk_bf16(f1.x * rv, f1.y * rv);
    w.w = pk_bf16(f1.z * rv, f1.w * rv);
    *(uint4*)(Xb + (size_t)row * D_DIM + lane * 8) = w;
}

// ---------------------------------------------------------------------------
// 256x256 8-wave bf16 GEMM, counted-vmcnt 4-deep pipeline (r11 K-loop,
// unchanged). r12 epilogue: row-major T2[128][136]; vector b128 scan reads;
// CONTIGUOUS 512B-per-row wave-level nontemporal sim stores (H4 test:
// prior epilogues scattered 16 rows x 64B per store instr; measured write
// BW 1.67 TB/s vs fillBuffer 6.6 TB/s).
// ---------------------------------------------------------------------------
__global__ __launch_bounds__(512, 2) void gemm256_fused(
        const unsigned short* __restrict__ Zb,
        const unsigned short* __restrict__ Pb,
        float* __restrict__ sim, uint2* __restrict__ part, int Pn) {
    extern __shared__ __align__(16) unsigned char SH[];
    uint4* S = (uint4*)SH;   // buf q: q*2048 + (A: 0..1023 | B: 1024..2047)

    int bi = blockIdx.x;
    int mb, nb;
    if (gridDim.x == 4096) {             // XCD chunk map (B=8192, P=32768)
        int xcd = bi & 7, r = bi >> 3;
        mb = xcd * 4 + (r & 3);          // 0..31
        nb = r >> 2;                     // 0..127
    } else {
        int nt = Pn >> 8;
        nb = bi % nt; mb = bi / nt;
    }
    const int bm = mb << 8, bn = nb << 8;

    const int tid = threadIdx.x;
    const int lane = tid & 63;
    const int wid = tid >> 6;
    const int wr = wid >> 2;             // 0..1
    const int wc = wid & 3;              // 0..3
    const int ln15 = lane & 15, hi = lane >> 4;

    // ---- staging addressing: per thread 2 chunks for A and 2 for B ----
    const int f0 = tid, f1 = 512 + tid;
    const int r0 = f0 >> 2, r1 = f1 >> 2;              // 0..127 / 128..255
    const int cg0 = (f0 & 3) ^ (r0 & 3);
    const int cg1 = (f1 & 3) ^ (r1 & 3);

    const unsigned short* pA0 = Zb + (size_t)(bm + r0) * D_DIM + cg0 * 8;
    const unsigned short* pA1 = Zb + (size_t)(bm + r1) * D_DIM + cg1 * 8;
    const unsigned short* pB0 = Pb + (size_t)(bn + r0) * D_DIM + cg0 * 8;
    const unsigned short* pB1 = Pb + (size_t)(bn + r1) * D_DIM + cg1 * 8;

#define ISSUE(qb)                                                    \
    do {                                                             \
        GLD_LDS16(pA0, &S[(qb) * 2048 + f0]);                        \
        GLD_LDS16(pA1, &S[(qb) * 2048 + f1]);                        \
        GLD_LDS16(pB0, &S[(qb) * 2048 + 1024 + f0]);                 \
        GLD_LDS16(pB1, &S[(qb) * 2048 + 1024 + f1]);                 \
        pA0 += 32; pA1 += 32; pB0 += 32; pB1 += 32;                  \
    } while (0)

    // ---- fragment read offsets (uint4 index within a buffer) ----
    const int sw = hi ^ (ln15 & 3);      // row&3 == ln15&3 for all frags
    int aOff[8], bOff[4];
#pragma unroll
    for (int m = 0; m < 8; ++m) aOff[m] = (wr * 128 + m * 16 + ln15) * 4 + sw;
#pragma unroll
    for (int n = 0; n < 4; ++n) bOff[n] = 1024 + (wc * 64 + n * 16 + ln15) * 4 + sw;

    f32x4 acc[8][4] = {};

    // ---- prologue: stage subtiles 0,1,2; certify 0; sync ----
    ISSUE(0); ISSUE(1); ISSUE(2);
    asm volatile("s_waitcnt vmcnt(8)" ::: "memory");
    __builtin_amdgcn_s_barrier();

#pragma unroll 1
    for (int s = 0; s < 16; ++s) {
        const int qb = s & 3;
        // reads of subtile s (certified at iter s-1 / prologue)
        bf16x8 av[8], bv[4];
#pragma unroll
        for (int mi = 0; mi < 8; ++mi)
            av[mi] = __builtin_bit_cast(bf16x8, S[qb * 2048 + aOff[mi]]);
#pragma unroll
        for (int ni = 0; ni < 4; ++ni)
            bv[ni] = __builtin_bit_cast(bf16x8, S[qb * 2048 + bOff[ni]]);
        // issue subtile s+3; counted wait certifies s+1 (never drain to 0)
        if (s < 13) {
            ISSUE((s + 3) & 3);
            asm volatile("s_waitcnt vmcnt(8)" ::: "memory");
        } else if (s == 13) {
            asm volatile("s_waitcnt vmcnt(4)" ::: "memory");
        } else {
            asm volatile("s_waitcnt vmcnt(0)" ::: "memory");
        }
        __builtin_amdgcn_s_barrier();
        asm volatile("s_waitcnt lgkmcnt(0)" ::: "memory");
        __builtin_amdgcn_sched_barrier(0);
        __builtin_amdgcn_s_setprio(1);
#pragma unroll
        for (int mi = 0; mi < 8; ++mi)
#pragma unroll
            for (int ni = 0; ni < 4; ++ni)
                acc[mi][ni] = __builtin_amdgcn_mfma_f32_16x16x32_bf16(
                    av[mi], bv[ni], acc[mi][ni], 0, 0, 0);
        __builtin_amdgcn_s_setprio(0);
        __builtin_amdgcn_sched_barrier(0);
        __builtin_amdgcn_s_barrier();
    }
#undef ISSUE

    // ---- r12 epilogue: row-major T2, vector scan, contiguous stores ----
    float* T2 = (float*)SH;              // [128 rows][136] f32 = 69632 B
    const int NB = Pn >> 8;
    const int r = tid >> 2;              // 0..127 (scan row)
    const int g = tid & 3;               // scan col group
    const int srl = lane >> 5;           // store: row-within-pair 0..1
    const int sc4 = (lane & 31) * 4;     // store: col (x4 floats)
#pragma unroll 1
    for (int hf = 0; hf < 2; ++hf) {
        float tv[4]; int ti[4];
#pragma unroll
        for (int k = 0; k < 4; ++k) { tv[k] = -FLT_MAX; ti[k] = 0x7FFFFFFF; }
#pragma unroll 1
        for (int ch = 0; ch < 2; ++ch) {
            __syncthreads();             // T2 free (prev phase readers done)
            if (wr == hf && (wc >> 1) == ch) {
#pragma unroll
                for (int m = 0; m < 8; ++m)
#pragma unroll
                    for (int n = 0; n < 4; ++n) {
                        int col = (wc & 1) * 64 + n * 16 + ln15;
#pragma unroll
                        for (int rr = 0; rr < 4; ++rr)
                            T2[(m * 16 + hi * 4 + rr) * 136 + col]
                                = acc[m][n][rr];
                    }
            }
            __syncthreads();
            const int colBase = bn + ch * 128;
            // scan: thread (r, g): 8 vector reads + gated INS4
#pragma unroll
            for (int j = 0; j < 8; ++j) {
                const int c0 = j * 16 + g * 4;
                f32x4 e = *(const f32x4*)&T2[r * 136 + c0];
                float mg = fmaxf(fmaxf(e[0], e[1]), fmaxf(e[2], e[3]));
                if (mg > tv[3]) {
                    INS4(e[0], colBase + c0 + 0, tv, ti);
                    INS4(e[1], colBase + c0 + 1, tv, ti);
                    INS4(e[2], colBase + c0 + 2, tv, ti);
                    INS4(e[3], colBase + c0 + 3, tv, ti);
                }
            }
            // contiguous store: wave wid -> rows wid*16..+15, 2 rows/instr;
            // each half-wave writes 512B contiguous of one sim row.
#pragma unroll
            for (int it = 0; it < 8; ++it) {
                int rowL = wid * 16 + it * 2 + srl;
                f32x4 v = *(const f32x4*)&T2[rowL * 136 + sc4];
                __builtin_nontemporal_store(v,
                    (f32x4*)&sim[(size_t)(bm + hf * 128 + rowL) * Pn
                                 + colBase + sc4]);
            }
        }
        // merge top-4 across the 4-lane col groups (lanes 4r..4r+3)
#pragma unroll
        for (int st = 1; st <= 2; st <<= 1) {
            float ov0 = __shfl_xor(tv[0], st), ov1 = __shfl_xor(tv[1], st);
            float ov2 = __shfl_xor(tv[2], st), ov3 = __shfl_xor(tv[3], st);
            int oi0 = __shfl_xor(ti[0], st), oi1 = __shfl_xor(ti[1], st);
            int oi2 = __shfl_xor(ti[2], st), oi3 = __shfl_xor(ti[3], st);
            INS4(ov0, oi0, tv, ti);
            INS4(ov1, oi1, tv, ti);
            INS4(ov2, oi2, tv, ti);
            INS4(ov3, oi3, tv, ti);
        }
        if (g == 0) {
            size_t o = ((size_t)(bm + hf * 128 + r) * NB + nb) * 4;
#pragma unroll
            for (int k = 0; k < 4; ++k)
                part[o + k] =
                    make_uint2(__builtin_bit_cast(uint32_t, tv[k]), (uint32_t)ti[k]);
        }
    }
}

// ---------------------------------------------------------------------------
// Reduce partial candidates (NB*4 per row) -> noisy top-8 -> exact f32
// rerank -> top-3. One wave per row.
// ---------------------------------------------------------------------------
__global__ __launch_bounds__(256) void topk_reduce(const uint2* __restrict__ part,
        const float* __restrict__ Z, const float* __restrict__ Pm,
        const float* __restrict__ rz, const float* __restrict__ rp,
        float* __restrict__ oidx, float* __restrict__ oval, int Pn, int NB) {
    int row = blockIdx.x * 4 + (threadIdx.x >> 6);
    int lane = threadIdx.x & 63;
    const uint2* pr = part + (size_t)row * NB * 4;

    float v[8]; int ix[8];
#pragma unroll
    for (int j = 0; j < 8; ++j) { v[j] = -FLT_MAX; ix[j] = -1; }

    const int total = NB * 4;
    for (int c = lane; c < total; c += 64) {
        uint2 u = pr[c];
        float val = __builtin_bit_cast(float, u.x);
        if (val > v[7]) {
            int idx = (int)u.y;
            int pos = 7;
#pragma unroll
            for (int j = 6; j >= 0; --j) {
                if (val > v[j]) { v[j+1] = v[j]; ix[j+1] = ix[j]; pos = j; }
            }
            v[pos] = val; ix[pos] = idx;
        }
    }

    int cand[8];
#pragma unroll
    for (int k = 0; k < 8; ++k) {
        float bv = v[0]; int bi2 = ix[0];
#pragma unroll
        for (int off = 32; off; off >>= 1) {
            float ov = __shfl_xor(bv, off);
            int oi = __shfl_xor(bi2, off);
            if (ov > bv || (ov == bv && oi >= 0 && (unsigned)oi < (unsigned)bi2)) {
                bv = ov; bi2 = oi;
            }
        }
        cand[k] = bi2;
        if (bi2 == ix[0]) {
#pragma unroll
            for (int j = 0; j < 7; ++j) { v[j] = v[j+1]; ix[j] = ix[j+1]; }
            v[7] = -FLT_MAX; ix[7] = -1;
        }
    }

    // exact f32 recompute of the 8 candidate similarities
    float zv[8];
    const float* zrow = Z + (size_t)row * D_DIM + lane * 8;
#pragma unroll
    for (int j = 0; j < 8; ++j) zv[j] = zrow[j];
    float rzv = rz[row];

    float ex[8];
#pragma unroll
    for (int c = 0; c < 8; ++c) {
        int idx = cand[c];
        const float* prow = Pm + (size_t)idx * D_DIM + lane * 8;
        float s = 0.f;
#pragma unroll
        for (int j = 0; j < 8; ++j) s += zv[j] * prow[j];
#pragma unroll
        for (int off = 32; off; off >>= 1) s += __shfl_xor(s, off);
        ex[c] = s * rzv * rp[idx];
    }

    bool used[8] = {};
#pragma unroll
    for (int k = 0; k < 3; ++k) {
        float bv = -FLT_MAX; int bi2 = Pn; int bc = 0;
#pragma unroll
        for (int c = 0; c < 8; ++c) {
            if (!used[c] && (ex[c] > bv || (ex[c] == bv && cand[c] < bi2))) {
                bv = ex[c]; bi2 = cand[c]; bc = c;
            }
        }
        used[bc] = true;
        if (lane == 0) {
            oidx[(size_t)row * 3 + k] = (float)bi2;
            oval[(size_t)row * 3 + k] = bv;
        }
    }
}

// ---------------------------------------------------------------------------
// Fallback: 128x128 2-phase kernel (attr failure / smaller ws).
// ---------------------------------------------------------------------------
template <bool FUSE>
__global__ __launch_bounds__(256, 4) void gemm_lds_bf16(
        const unsigned short* __restrict__ Zb,
        const unsigned short* __restrict__ Pb,
        float* __restrict__ sim, uint2* __restrict__ part, int Pn) {
    __shared__ __align__(16) unsigned char SHs[32768];
    uint4* S = (uint4*)SHs;

    int bi = blockIdx.x;
    int mb, nb;
    if (gridDim.x == 16384) {
        int xcd = bi & 7;
        int r = bi >> 3;
        mb = xcd * 8 + (r & 7);
        nb = r >> 3;
    } else {
        nb = bi % (Pn / 128);
        mb = bi / (Pn / 128);
    }
    const int bm = mb * 128, bn = nb * 128;

    const int tid = threadIdx.x;
    const int lane = tid & 63;
    const int wid = tid >> 6;
    const int wr = wid >> 1, wc = wid & 1;
    const int ln15 = lane & 15, hi = lane >> 4;

    const unsigned short* gA[2];
    const unsigned short* gB[2];
    int ldsIdx[2];
#pragma unroll
    for (int q = 0; q < 2; ++q) {
        int flat = q * 256 + tid;
        int row = flat >> 2;
        int c = flat & 3;
        int cg = c ^ (row & 3);
        gA[q] = Zb + (size_t)(bm + row) * D_DIM + cg * 8;
        gB[q] = Pb + (size_t)(bn + row) * D_DIM + cg * 8;
        ldsIdx[q] = flat;
    }

    f32x4 acc[4][4] = {};

#pragma unroll
    for (int q = 0; q < 2; ++q) {
        GLD_LDS16(gA[q], &S[ldsIdx[q]]);
        GLD_LDS16(gB[q], &S[512 + ldsIdx[q]]);
        gA[q] += 32;
        gB[q] += 32;
    }

    int cur = 0;
#pragma unroll 1
    for (int s8 = 0; s8 < 16; ++s8) {
        const int nxt = cur ^ 1;
        if (s8 < 15) {
#pragma unroll
            for (int q = 0; q < 2; ++q) {
                GLD_LDS16(gA[q], &S[nxt * 1024 + ldsIdx[q]]);
                GLD_LDS16(gB[q], &S[nxt * 1024 + 512 + ldsIdx[q]]);
                gA[q] += 32;
                gB[q] += 32;
            }
            asm volatile("s_waitcnt vmcnt(4)" ::: "memory");
        } else {
            asm volatile("s_waitcnt vmcnt(0)" ::: "memory");
        }
        __builtin_amdgcn_s_barrier();
        __builtin_amdgcn_sched_barrier(0);

        const int sb = cur * 1024;
        __builtin_amdgcn_s_setprio(1);
        bf16x8 av[4], bv[4];
#pragma unroll
        for (int t = 0; t < 4; ++t) {
            int arow = wr * 64 + t * 16 + ln15;
            av[t] = __builtin_bit_cast(bf16x8,
                    S[sb + arow * 4 + (hi ^ (arow & 3))]);
            int brow = wc * 64 + t * 16 + ln15;
            bv[t] = __builtin_bit_cast(bf16x8,
                    S[sb + 512 + brow * 4 + (hi ^ (brow & 3))]);
        }
#pragma unroll
        for (int i = 0; i < 4; ++i)
#pragma unroll
            for (int j = 0; j < 4; ++j)
                acc[i][j] = __builtin_amdgcn_mfma_f32_16x16x32_bf16(
                    av[i], bv[j], acc[i][j], 0, 0, 0);
        __builtin_amdgcn_s_setprio(0);
        __builtin_amdgcn_sched_barrier(0);
        __builtin_amdgcn_s_barrier();
        cur = nxt;
    }

#pragma unroll
    for (int i = 0; i < 4; ++i) {
#pragma unroll
        for (int rr = 0; rr < 4; ++rr) {
            int row = bm + wr * 64 + i * 16 + hi * 4 + rr;
#pragma unroll
            for (int j = 0; j < 4; ++j) {
                int col = bn + wc * 64 + j * 16 + ln15;
                sim[(size_t)row * Pn + col] = acc[i][j][rr];
            }
        }
    }

    if constexpr (FUSE) {
        float* T = (float*)SHs;
        uint2* M = (uint2*)(SHs + 17408);
        const int NB = Pn >> 7;
        const int r = tid & 63;
        const int q = tid >> 6;
#pragma unroll 1
        for (int hf = 0; hf < 2; ++hf) {
            float rv[4]; int ri[4];
#pragma unroll
            for (int k = 0; k < 4; ++k) { rv[k] = -FLT_MAX; ri[k] = 0x7FFFFFFF; }
#pragma unroll 1
            for (int ch = 0; ch < 2; ++ch) {
                __syncthreads();
                if (wr == hf && wc == ch) {
#pragma unroll
                    for (int i = 0; i < 4; ++i)
#pragma unroll
                        for (int j = 0; j < 4; ++j)
                            *(f32x4*)&T[(j * 16 + ln15) * 68 + i * 16 + hi * 4]
                                = acc[i][j];
                }
                __syncthreads();
                float tv[4]; int ti[4];
#pragma unroll
                for (int k = 0; k < 4; ++k) { tv[k] = -FLT_MAX; ti[k] = 0x7FFFFFFF; }
#pragma unroll
                for (int c4 = 0; c4 < 16; c4 += 4) {
                    float e0 = T[(q * 16 + c4 + 0) * 68 + r];
                    float e1 = T[(q * 16 + c4 + 1) * 68 + r];
                    float e2 = T[(q * 16 + c4 + 2) * 68 + r];
                    float e3 = T[(q * 16 + c4 + 3) * 68 + r];
                    float mg = fmaxf(fmaxf(e0, e1), fmaxf(e2, e3));
                    if (mg > tv[3]) {
                        int cb = bn + ch * 64 + q * 16 + c4;
                        INS4(e0, cb + 0, tv, ti);
                        INS4(e1, cb + 1, tv, ti);
                        INS4(e2, cb + 2, tv, ti);
                        INS4(e3, cb + 3, tv, ti);
                    }
                }
#pragma unroll
                for (int k = 0; k < 4; ++k)
                    M[q * 256 + k * 64 + r] =
                        make_uint2(__builtin_bit_cast(uint32_t, tv[k]), (uint32_t)ti[k]);
                __syncthreads();
                if (tid < 64) {
#pragma unroll
                    for (int qq = 0; qq < 4; ++qq)
#pragma unroll
                        for (int k = 0; k < 4; ++k) {
                            uint2 u = M[qq * 256 + k * 64 + tid];
                            float val = __builtin_bit_cast(float, u.x);
                            INS4(val, (int)u.y, rv, ri);
                        }
                }
            }
            if (tid < 64) {
                size_t o = ((size_t)(bm + hf * 64 + tid) * NB + nb) * 4;
#pragma unroll
                for (int k = 0; k < 4; ++k)
                    part[o + k] =
                        make_uint2(__builtin_bit_cast(uint32_t, rv[k]), (uint32_t)ri[k]);
            }
        }
    }
}

// ---------------------------------------------------------------------------
// Deep fallbacks: f32-input GEMM + full-sim topk (tiny ws).
// ---------------------------------------------------------------------------
__global__ __launch_bounds__(256) void rnorm_kernel(const float* __restrict__ X,
                                                    float* __restrict__ r, int R) {
    int row = blockIdx.x * 4 + (threadIdx.x >> 6);
    if (row >= R) return;
    int lane = threadIdx.x & 63;
    const float* x = X + (size_t)row * D_DIM;
    float s = 0.f;
#pragma unroll
    for (int t = 0; t < 2; ++t) {
        float4 v = *(const float4*)(x + (t * 64 + lane) * 4);
        s += v.x * v.x + v.y * v.y + v.z * v.z + v.w * v.w;
    }
#pragma unroll
    for (int off = 32; off; off >>= 1) s += __shfl_xor(s, off);
    if (lane == 0) r[row] = 1.0f / fmaxf(sqrtf(s), 1e-12f);
}

__global__ __launch_bounds__(256, 2) void gemm_bf16_sim(const float* __restrict__ Z,
        const float* __restrict__ Pm, const float* __restrict__ rz,
        const float* __restrict__ rp, float* __restrict__ sim, int Pn) {
    __shared__ uint4 As16[1024];
    __shared__ uint4 Bs16[1024];
    int bi = blockIdx.x;
    int nb = bi % (Pn / 128);
    int mb = bi / (Pn / 128);
    const int bm = mb * 128, bn = nb * 128;
    const int tid = threadIdx.x;
    const int srow = tid >> 1;
    const int half = tid & 1;
    const float* aP = Z  + (size_t)(bm + srow) * D_DIM + half * 32;
    const float* bP = Pm + (size_t)(bn + srow) * D_DIM + half * 32;
    const int lane = tid & 63;
    const int wid = tid >> 6;
    const int wr = wid >> 1, wc = wid & 1;
    const int ln15 = lane & 15, hi = lane >> 4;
    f32x4 acc[4][4] = {};
    float4 f[8], g[8];
#pragma unroll
    for (int q = 0; q < 8; ++q) {
        f[q] = *(const float4*)(aP + q * 4);
        g[q] = *(const float4*)(bP + q * 4);
    }
#pragma unroll 1
    for (int s = 0; s < 8; ++s) {
#pragma unroll
        for (int q8 = 0; q8 < 4; ++q8) {
            uint4 wa, wb;
            wa.x = pk_bf16(f[2*q8].x,   f[2*q8].y);
            wa.y = pk_bf16(f[2*q8].z,   f[2*q8].w);
            wa.z = pk_bf16(f[2*q8+1].x, f[2*q8+1].y);
            wa.w = pk_bf16(f[2*q8+1].z, f[2*q8+1].w);
            wb.x = pk_bf16(g[2*q8].x,   g[2*q8].y);
            wb.y = pk_bf16(g[2*q8].z,   g[2*q8].w);
            wb.z = pk_bf16(g[2*q8+1].x, g[2*q8+1].y);
            wb.w = pk_bf16(g[2*q8+1].z, g[2*q8+1].w);
            int colByte = half * 64 + q8 * 16;
            int idx = srow * 8 + ((colByte ^ ((srow & 7) << 4)) >> 4);
            As16[idx] = wa;
            Bs16[idx] = wb;
        }
        __syncthreads();
        if (s < 7) {
            int k0 = (s + 1) * 64;
#pragma unroll
            for (int q = 0; q < 8; ++q) {
                f[q] = *(const float4*)(aP + k0 + q * 4);
                g[q] = *(const float4*)(bP + k0 + q * 4);
            }
        }
#pragma unroll
        for (int kk = 0; kk < 2; ++kk) {
            bf16x8 av[4], bv[4];
            const int cb = kk * 64 + hi * 16;
#pragma unroll
            for (int t = 0; t < 4; ++t) {
                int arow = wr * 64 + t * 16 + ln15;
                av[t] = __builtin_bit_cast(bf16x8,
                        As16[arow * 8 + ((cb ^ ((arow & 7) << 4)) >> 4)]);
                int brow = wc * 64 + t * 16 + ln15;
                bv[t] = __builtin_bit_cast(bf16x8,
                        Bs16[brow * 8 + ((cb ^ ((brow & 7) << 4)) >> 4)]);
            }
#pragma unroll
            for (int i = 0; i < 4; ++i)
#pragma unroll
                for (int j = 0; j < 4; ++j)
                    acc[i][j] = __builtin_amdgcn_mfma_f32_16x16x32_bf16(
                        av[i], bv[j], acc[i][j], 0, 0, 0);
        }
        __syncthreads();
    }
    float rpv[4];
#pragma unroll
    for (int j = 0; j < 4; ++j) rpv[j] = rp[bn + wc * 64 + j * 16 + ln15];
#pragma unroll
    for (int i = 0; i < 4; ++i) {
#pragma unroll
        for (int rr = 0; rr < 4; ++rr) {
            int row = bm + wr * 64 + i * 16 + hi * 4 + rr;
            float rzv = rz[row];
#pragma unroll
            for (int j = 0; j < 4; ++j) {
                int col = bn + wc * 64 + j * 16 + ln15;
                sim[(size_t)row * Pn + col] = acc[i][j][rr] * rzv * rpv[j];
            }
        }
    }
}

__global__ __launch_bounds__(256) void topk_refine(const float* __restrict__ sim,
        const float* __restrict__ Z, const float* __restrict__ Pm,
        const float* __restrict__ rz, const float* __restrict__ rp,
        float* __restrict__ oidx, float* __restrict__ oval, int Pn) {
    int row = blockIdx.x * 4 + (threadIdx.x >> 6);
    int lane = threadIdx.x & 63;
    const float* rptr = sim + (size_t)row * Pn;

    float v[8]; int ix[8];
#pragma unroll
    for (int j = 0; j < 8; ++j) { v[j] = -FLT_MAX; ix[j] = -1; }

    const int iters = Pn >> 8;
    for (int t = 0; t < iters; ++t) {
        int base = t * 256 + lane * 4;
        float4 q = *(const float4*)(rptr + base);
        float vals[4] = {q.x, q.y, q.z, q.w};
#pragma unroll
        for (int e = 0; e < 4; ++e) {
            float val = vals[e];
            if (val > v[7]) {
                int idx = base + e;
                int pos = 7;
#pragma unroll
                for (int j = 6; j >= 0; --j) {
                    if (val > v[j]) { v[j+1] = v[j]; ix[j+1] = ix[j]; pos = j; }
                }
                v[pos] = val; ix[pos] = idx;
            }
        }
    }

    int cand[8];
#pragma unroll
    for (int k = 0; k < 8; ++k) {
        float bv = v[0]; int bi2 = ix[0];
#pragma unroll
        for (int off = 32; off; off >>= 1) {
            float ov = __shfl_xor(bv, off);
            int oi = __shfl_xor(bi2, off);
            if (ov > bv || (ov == bv && oi >= 0 && (unsigned)oi < (unsigned)bi2)) {
                bv = ov; bi2 = oi;
            }
        }
        cand[k] = bi2;
        if (bi2 == ix[0]) {
#pragma unroll
            for (int j = 0; j < 7; ++j) { v[j] = v[j+1]; ix[j] = ix[j+1]; }
            v[7] = -FLT_MAX; ix[7] = -1;
        }
    }

    float zv[8];
    const float* zrow = Z + (size_t)row * D_DIM + lane * 8;
#pragma unroll
    for (int j = 0; j < 8; ++j) zv[j] = zrow[j];
    float rzv = rz[row];

    float ex[8];
#pragma unroll
    for (int c = 0; c < 8; ++c) {
        int idx = cand[c];
        const float* prow = Pm + (size_t)idx * D_DIM + lane * 8;
        float s = 0.f;
#pragma unroll
        for (int j = 0; j < 8; ++j) s += zv[j] * prow[j];
#pragma unroll
        for (int off = 32; off; off >>= 1) s += __shfl_xor(s, off);
        ex[c] = s * rzv * rp[idx];
    }

    bool used[8] = {};
#pragma unroll
    for (int k = 0; k < 3; ++k) {
        float bv = -FLT_MAX; int bi2 = Pn; int bc = 0;
#pragma unroll
        for (int c = 0; c < 8; ++c) {
            if (!used[c] && (ex[c] > bv || (ex[c] == bv && cand[c] < bi2))) {
                bv = ex[c]; bi2 = cand[c]; bc = c;
            }
        }
        used[bc] = true;
        if (lane == 0) {
            oidx[(size_t)row * 3 + k] = (float)bi2;
            oval[(size_t)row * 3 + k] = bv;
        }
    }
}

extern "C" void kernel_launch(void* const* d_in, const int* in_sizes, int n_in,
                              void* d_out, int out_size, void* d_ws, size_t ws_size,
                              hipStream_t stream) {
    const float* Z  = (const float*)d_in[0];   // [B, 512]
    const float* Pm = (const float*)d_in[1];   // [P, 512]
    const int B  = in_sizes[0] / D_DIM;        // 8192
    const int Pn = in_sizes[1] / D_DIM;        // 32768

    float* sim  = (float*)d_out;
    float* oidx = sim + (size_t)B * Pn;
    float* oval = oidx + (size_t)B * 3;

    float* rz = (float*)d_ws;
    float* rp = rz + B;
    unsigned short* Zb = (unsigned short*)(rp + Pn);
    unsigned short* Pb = Zb + (size_t)B * D_DIM;
    uint2* part = (uint2*)(Pb + (size_t)Pn * D_DIM);

    const size_t need_bf16 = (size_t)(B + Pn) * 4 + (size_t)(B + Pn) * D_DIM * 2;
    const size_t need256 = need_bf16 + (size_t)B * (Pn >> 8) * 4 * sizeof(uint2);
    const size_t need128 = need_bf16 + (size_t)B * (Pn >> 7) * 4 * sizeof(uint2);

    bool big = false;
    if ((B & 255) == 0 && (Pn & 255) == 0 && ws_size >= need256) {
        big = (hipFuncSetAttribute((const void*)gemm256_fused,
                   hipFuncAttributeMaxDynamicSharedMemorySize,
                   131072) == hipSuccess);
    }

    if (big) {
        convert_norm_kernel<<<B / 4, 256, 0, stream>>>(Z, Zb, rz, B);
        convert_norm_kernel<<<Pn / 4, 256, 0, stream>>>(Pm, Pb, rp, Pn);
        gemm256_fused<<<(B / 256) * (Pn / 256), 512, 131072, stream>>>(
            Zb, Pb, sim, part, Pn);
        topk_reduce<<<B / 4, 256, 0, stream>>>(part, Z, Pm, rz, rp,
                                               oidx, oval, Pn, Pn >> 8);
    } else if (ws_size >= need128) {
        convert_norm_kernel<<<B / 4, 256, 0, stream>>>(Z, Zb, rz, B);
        convert_norm_kernel<<<Pn / 4, 256, 0, stream>>>(Pm, Pb, rp, Pn);
        gemm_lds_bf16<true><<<(B / 128) * (Pn / 128), 256, 0, stream>>>(
            Zb, Pb, sim, part, Pn);
        topk_reduce<<<B / 4, 256, 0, stream>>>(part, Z, Pm, rz, rp,
                                               oidx, oval, Pn, Pn >> 7);
    } else if (ws_size >= need_bf16) {
        convert_norm_kernel<<<B / 4, 256, 0, stream>>>(Z, Zb, rz, B);
        convert_norm_kernel<<<Pn / 4, 256, 0, stream>>>(Pm, Pb, rp, Pn);
        gemm_lds_bf16<false><<<(B / 128) * (Pn / 128), 256, 0, stream>>>(
            Zb, Pb, sim, nullptr, Pn);
        topk_refine<<<B / 4, 256, 0, stream>>>(sim, Z, Pm, rz, rp, oidx, oval, Pn);
    } else {
        rnorm_kernel<<<B / 4, 256, 0, stream>>>(Z, rz, B);
        rnorm_kernel<<<Pn / 4, 256, 0, stream>>>(Pm, rp, Pn);
        gemm_bf16_sim<<<(B / 128) * (Pn / 128), 256, 0, stream>>>(
            Z, Pm, rz, rp, sim, Pn);
        topk_refine<<<B / 4, 256, 0, stream>>>(sim, Z, Pm, rz, rp, oidx, oval, Pn);
    }
}

// Round 14
// 635.648 us; speedup vs baseline: 1.0739x; 1.0619x over previous
//
#include <hip/hip_runtime.h>
#include <float.h>
#include <stdint.h>

#define D_DIM 512

typedef __attribute__((ext_vector_type(8))) short bf16x8;
typedef __attribute__((ext_vector_type(4))) float f32x4;

// async global->LDS, 16B per lane (linear LDS dest: wave base + lane*16)
#define GLD_LDS16(g, l)                                              \
    __builtin_amdgcn_global_load_lds(                                \
        (const __attribute__((address_space(1))) void*)(g),          \
        (__attribute__((address_space(3))) void*)(l), 16, 0, 0)

// round-half-up f32->bf16, pack two into one u32
__device__ __forceinline__ uint32_t pk_bf16(float a, float b) {
    uint32_t ua = __builtin_bit_cast(uint32_t, a) + 0x8000u;
    uint32_t ub = __builtin_bit_cast(uint32_t, b) + 0x8000u;
    return (ua >> 16) | (ub & 0xFFFF0000u);
}

// sorted-desc top-4 insert, static indices only
#define INS4(val, idx, tv, ti)                                        \
    if ((val) > tv[3]) {                                              \
        int p_ = 3;                                                   \
        if ((val) > tv[2]) { tv[3] = tv[2]; ti[3] = ti[2]; p_ = 2; }  \
        if ((val) > tv[1]) { tv[2] = tv[1]; ti[2] = ti[1]; p_ = 1; }  \
        if ((val) > tv[0]) { tv[1] = tv[0]; ti[1] = ti[0]; p_ = 0; }  \
        tv[p_] = (val); ti[p_] = (idx);                               \
    }

// ---------------------------------------------------------------------------
// Per-row: r[row] = 1/max(||X[row]||,eps); Xb[row,:] = bf16(X[row,:] * r).
// ---------------------------------------------------------------------------
__global__ __launch_bounds__(256) void convert_norm_kernel(
        const float* __restrict__ X, unsigned short* __restrict__ Xb,
        float* __restrict__ r, int R) {
    int row = blockIdx.x * 4 + (threadIdx.x >> 6);
    if (row >= R) return;
    int lane = threadIdx.x & 63;
    const float* x = X + (size_t)row * D_DIM + lane * 8;
    float4 f0 = *(const float4*)(x);
    float4 f1 = *(const float4*)(x + 4);
    float s = f0.x*f0.x + f0.y*f0.y + f0.z*f0.z + f0.w*f0.w
            + f1.x*f1.x + f1.y*f1.y + f1.z*f1.z + f1.w*f1.w;
#pragma unroll
    for (int off = 32; off; off >>= 1) s += __shfl_xor(s, off);
    float rv = 1.0f / fmaxf(sqrtf(s), 1e-12f);
    if (lane == 0) r[row] = rv;
    uint4 w;
    w.x = pk_bf16(f0.x * rv, f0.y * rv);
    w.y = pk_bf16(f0.z * rv, f0.w * rv);
    w.z = pk_bf16(f1.x * rv, f1.y * rv);
    w.w = pk_bf16(f1.z * rv, f1.w * rv);
    *(uint4*)(Xb + (size_t)row * D_DIM + lane * 8) = w;
}

// ---------------------------------------------------------------------------
// 256x256 8-wave bf16 GEMM, r13/r14: overlapped-read pipeline + 2-way swizzle.
// BK=32 subtiles (16), 4 LDS buffers (128KB dynamic).
// Interval s: {ds_read subtile s+1 -> other reg set (OVERLAPS MFMA below)
//   || ISSUE(s+3)} -> MFMA(s) on current reg set -> lgkm(0) (drain s+1
//   reads) -> counted vmcnt (certify s+2; never drains mid-loop) -> barrier.
// Buffer safety: reads of buf[q] drain before the interval's barrier; its
// overwrite (ISSUE) happens >= 2 barriers later in the 4-buffer rotation.
// Swizzle g(row)=(row>>1)&3 on BOTH global source and ds_read -> 2-way
// bank aliasing (free), vs r12's row&3 (4-way, 37.7M conflict-cycles).
// Fused epilogue: row-major T2, vector scan, contiguous nontemporal stores.
// ---------------------------------------------------------------------------
__global__ __launch_bounds__(512, 2) void gemm256_fused(
        const unsigned short* __restrict__ Zb,
        const unsigned short* __restrict__ Pb,
        float* __restrict__ sim, uint2* __restrict__ part, int Pn) {
    extern __shared__ __align__(16) unsigned char SH[];
    uint4* S = (uint4*)SH;   // buf q: q*2048 + (A: 0..1023 | B: 1024..2047)

    int bi = blockIdx.x;
    int mb, nb;
    if (gridDim.x == 4096) {             // XCD chunk map (B=8192, P=32768)
        int xcd = bi & 7, r = bi >> 3;
        mb = xcd * 4 + (r & 3);          // 0..31
        nb = r >> 2;                     // 0..127
    } else {
        int nt = Pn >> 8;
        nb = bi % nt; mb = bi / nt;
    }
    const int bm = mb << 8, bn = nb << 8;

    const int tid = threadIdx.x;
    const int lane = tid & 63;
    const int wid = tid >> 6;
    const int wr = wid >> 2;             // 0..1
    const int wc = wid & 3;              // 0..3
    const int ln15 = lane & 15, hi = lane >> 4;

    // ---- staging addressing: per thread 2 chunks for A and 2 for B ----
    const int f0 = tid, f1 = 512 + tid;
    // LDS slot (row,c) holds global chunk c ^ ((row>>1)&3); row=f>>2, c=f&3
    const int cg0 = (f0 & 3) ^ ((f0 >> 3) & 3);
    const int cg1 = (f1 & 3) ^ ((f1 >> 3) & 3);
    const int r0 = f0 >> 2, r1 = f1 >> 2;

    const unsigned short* pA0 = Zb + (size_t)(bm + r0) * D_DIM + cg0 * 8;
    const unsigned short* pA1 = Zb + (size_t)(bm + r1) * D_DIM + cg1 * 8;
    const unsigned short* pB0 = Pb + (size_t)(bn + r0) * D_DIM + cg0 * 8;
    const unsigned short* pB1 = Pb + (size_t)(bn + r1) * D_DIM + cg1 * 8;

#define ISSUE(qb)                                                    \
    do {                                                             \
        GLD_LDS16(pA0, &S[(qb) * 2048 + f0]);                        \
        GLD_LDS16(pA1, &S[(qb) * 2048 + f1]);                        \
        GLD_LDS16(pB0, &S[(qb) * 2048 + 1024 + f0]);                 \
        GLD_LDS16(pB1, &S[(qb) * 2048 + 1024 + f1]);                 \
        pA0 += 32; pA1 += 32; pB0 += 32; pB1 += 32;                  \
    } while (0)

    // ---- fragment read offsets: chunk = hi ^ ((row>>1)&3); for all frag
    // rows, (row>>1)&3 == (ln15>>1)&3 (row = 16k + ln15, 16k mult of 8) ----
    const int sw = hi ^ ((ln15 >> 1) & 3);
    int aOff[8], bOff[4];
#pragma unroll
    for (int m = 0; m < 8; ++m) aOff[m] = (wr * 128 + m * 16 + ln15) * 4 + sw;
#pragma unroll
    for (int n = 0; n < 4; ++n) bOff[n] = 1024 + (wc * 64 + n * 16 + ln15) * 4 + sw;

    f32x4 acc[8][4] = {};
    bf16x8 Xa[8], Xb4[4], Ya[8], Yb4[4];

    // ---- prologue: stage 0,1,2; certify 0 AND 1; read subtile 0 -> X ----
    ISSUE(0); ISSUE(1); ISSUE(2);
    asm volatile("s_waitcnt vmcnt(4)" ::: "memory");
    __builtin_amdgcn_s_barrier();
    {
#pragma unroll
        for (int mi = 0; mi < 8; ++mi)
            Xa[mi] = __builtin_bit_cast(bf16x8, S[aOff[mi]]);
#pragma unroll
        for (int ni = 0; ni < 4; ++ni)
            Xb4[ni] = __builtin_bit_cast(bf16x8, S[bOff[ni]]);
    }

#pragma unroll 1
    for (int s2 = 0; s2 < 8; ++s2) {
        const int s0 = s2 * 2;
        // ---- interval s0: prefetch Y <- subtile s0+1; MFMA on X ----
        {
#pragma unroll
            for (int mi = 0; mi < 8; ++mi)
                Ya[mi] = __builtin_bit_cast(bf16x8,
                             S[((s0 + 1) & 3) * 2048 + aOff[mi]]);
#pragma unroll
            for (int ni = 0; ni < 4; ++ni)
                Yb4[ni] = __builtin_bit_cast(bf16x8,
                             S[((s0 + 1) & 3) * 2048 + bOff[ni]]);
        }
        if (s0 <= 12) ISSUE((s0 + 3) & 3);
        __builtin_amdgcn_s_setprio(1);
#pragma unroll
        for (int mi = 0; mi < 8; ++mi)
#pragma unroll
            for (int ni = 0; ni < 4; ++ni)
                acc[mi][ni] = __builtin_amdgcn_mfma_f32_16x16x32_bf16(
                    Xa[mi], Xb4[ni], acc[mi][ni], 0, 0, 0);
        __builtin_amdgcn_s_setprio(0);
        asm volatile("s_waitcnt lgkmcnt(0)" ::: "memory");
        if (s0 <= 12) asm volatile("s_waitcnt vmcnt(4)" ::: "memory");
        else          asm volatile("s_waitcnt vmcnt(0)" ::: "memory");
        __builtin_amdgcn_sched_barrier(0);
        __builtin_amdgcn_s_barrier();

        // ---- interval s1=s0+1: prefetch X <- subtile s1+1; MFMA on Y ----
        const int s1 = s0 + 1;
        if (s1 < 15) {
#pragma unroll
            for (int mi = 0; mi < 8; ++mi)
                Xa[mi] = __builtin_bit_cast(bf16x8,
                             S[((s1 + 1) & 3) * 2048 + aOff[mi]]);
#pragma unroll
            for (int ni = 0; ni < 4; ++ni)
                Xb4[ni] = __builtin_bit_cast(bf16x8,
                             S[((s1 + 1) & 3) * 2048 + bOff[ni]]);
        }
        if (s1 <= 12) ISSUE((s1 + 3) & 3);
        __builtin_amdgcn_s_setprio(1);
#pragma unroll
        for (int mi = 0; mi < 8; ++mi)
#pragma unroll
            for (int ni = 0; ni < 4; ++ni)
                acc[mi][ni] = __builtin_amdgcn_mfma_f32_16x16x32_bf16(
                    Ya[mi], Yb4[ni], acc[mi][ni], 0, 0, 0);
        __builtin_amdgcn_s_setprio(0);
        if (s1 < 15) {
            asm volatile("s_waitcnt lgkmcnt(0)" ::: "memory");
            if (s1 <= 12) asm volatile("s_waitcnt vmcnt(4)" ::: "memory");
            else          asm volatile("s_waitcnt vmcnt(0)" ::: "memory");
            __builtin_amdgcn_sched_barrier(0);
            __builtin_amdgcn_s_barrier();
        }
    }
#undef ISSUE

    // ---- fused epilogue: row-major T2, vector scan, contiguous stores ----
    float* T2 = (float*)SH;              // [128 rows][136] f32 = 69632 B
    const int NB = Pn >> 8;
    const int r = tid >> 2;              // 0..127 (scan row)
    const int g = tid & 3;               // scan col group
    const int srl = lane >> 5;           // store: row-within-pair 0..1
    const int sc4 = (lane & 31) * 4;     // store: col (x4 floats)
#pragma unroll 1
    for (int hf = 0; hf < 2; ++hf) {
        float tv[4]; int ti[4];
#pragma unroll
        for (int k = 0; k < 4; ++k) { tv[k] = -FLT_MAX; ti[k] = 0x7FFFFFFF; }
#pragma unroll 1
        for (int ch = 0; ch < 2; ++ch) {
            __syncthreads();             // T2 free (prev phase readers done)
            if (wr == hf && (wc >> 1) == ch) {
#pragma unroll
                for (int m = 0; m < 8; ++m)
#pragma unroll
                    for (int n = 0; n < 4; ++n) {
                        int col = (wc & 1) * 64 + n * 16 + ln15;
#pragma unroll
                        for (int rr = 0; rr < 4; ++rr)
                            T2[(m * 16 + hi * 4 + rr) * 136 + col]
                                = acc[m][n][rr];
                    }
            }
            __syncthreads();
            const int colBase = bn + ch * 128;
            // scan: thread (r, g): 8 vector reads + gated INS4
#pragma unroll
            for (int j = 0; j < 8; ++j) {
                const int c0 = j * 16 + g * 4;
                f32x4 e = *(const f32x4*)&T2[r * 136 + c0];
                float mg = fmaxf(fmaxf(e[0], e[1]), fmaxf(e[2], e[3]));
                if (mg > tv[3]) {
                    INS4(e[0], colBase + c0 + 0, tv, ti);
                    INS4(e[1], colBase + c0 + 1, tv, ti);
                    INS4(e[2], colBase + c0 + 2, tv, ti);
                    INS4(e[3], colBase + c0 + 3, tv, ti);
                }
            }
            // contiguous store: wave wid -> rows wid*16..+15, 2 rows/instr
#pragma unroll
            for (int it = 0; it < 8; ++it) {
                int rowL = wid * 16 + it * 2 + srl;
                f32x4 v = *(const f32x4*)&T2[rowL * 136 + sc4];
                __builtin_nontemporal_store(v,
                    (f32x4*)&sim[(size_t)(bm + hf * 128 + rowL) * Pn
                                 + colBase + sc4]);
            }
        }
        // merge top-4 across the 4-lane col groups (lanes 4r..4r+3)
#pragma unroll
        for (int st = 1; st <= 2; st <<= 1) {
            float ov0 = __shfl_xor(tv[0], st), ov1 = __shfl_xor(tv[1], st);
            float ov2 = __shfl_xor(tv[2], st), ov3 = __shfl_xor(tv[3], st);
            int oi0 = __shfl_xor(ti[0], st), oi1 = __shfl_xor(ti[1], st);
            int oi2 = __shfl_xor(ti[2], st), oi3 = __shfl_xor(ti[3], st);
            INS4(ov0, oi0, tv, ti);
            INS4(ov1, oi1, tv, ti);
            INS4(ov2, oi2, tv, ti);
            INS4(ov3, oi3, tv, ti);
        }
        if (g == 0) {
            size_t o = ((size_t)(bm + hf * 128 + r) * NB + nb) * 4;
#pragma unroll
            for (int k = 0; k < 4; ++k)
                part[o + k] =
                    make_uint2(__builtin_bit_cast(uint32_t, tv[k]), (uint32_t)ti[k]);
        }
    }
}

// ---------------------------------------------------------------------------
// Reduce partial candidates (NB*4 per row) -> noisy top-8 -> exact f32
// rerank -> top-3. One wave per row.
// ---------------------------------------------------------------------------
__global__ __launch_bounds__(256) void topk_reduce(const uint2* __restrict__ part,
        const float* __restrict__ Z, const float* __restrict__ Pm,
        const float* __restrict__ rz, const float* __restrict__ rp,
        float* __restrict__ oidx, float* __restrict__ oval, int Pn, int NB) {
    int row = blockIdx.x * 4 + (threadIdx.x >> 6);
    int lane = threadIdx.x & 63;
    const uint2* pr = part + (size_t)row * NB * 4;

    float v[8]; int ix[8];
#pragma unroll
    for (int j = 0; j < 8; ++j) { v[j] = -FLT_MAX; ix[j] = -1; }

    const int total = NB * 4;
    for (int c = lane; c < total; c += 64) {
        uint2 u = pr[c];
        float val = __builtin_bit_cast(float, u.x);
        if (val > v[7]) {
            int idx = (int)u.y;
            int pos = 7;
#pragma unroll
            for (int j = 6; j >= 0; --j) {
                if (val > v[j]) { v[j+1] = v[j]; ix[j+1] = ix[j]; pos = j; }
            }
            v[pos] = val; ix[pos] = idx;
        }
    }

    int cand[8];
#pragma unroll
    for (int k = 0; k < 8; ++k) {
        float bv = v[0]; int bi2 = ix[0];
#pragma unroll
        for (int off = 32; off; off >>= 1) {
            float ov = __shfl_xor(bv, off);
            int oi = __shfl_xor(bi2, off);
            if (ov > bv || (ov == bv && oi >= 0 && (unsigned)oi < (unsigned)bi2)) {
                bv = ov; bi2 = oi;
            }
        }
        cand[k] = bi2;
        if (bi2 == ix[0]) {
#pragma unroll
            for (int j = 0; j < 7; ++j) { v[j] = v[j+1]; ix[j] = ix[j+1]; }
            v[7] = -FLT_MAX; ix[7] = -1;
        }
    }

    // exact f32 recompute of the 8 candidate similarities
    float zv[8];
    const float* zrow = Z + (size_t)row * D_DIM + lane * 8;
#pragma unroll
    for (int j = 0; j < 8; ++j) zv[j] = zrow[j];
    float rzv = rz[row];

    float ex[8];
#pragma unroll
    for (int c = 0; c < 8; ++c) {
        int idx = cand[c];
        const float* prow = Pm + (size_t)idx * D_DIM + lane * 8;
        float s = 0.f;
#pragma unroll
        for (int j = 0; j < 8; ++j) s += zv[j] * prow[j];
#pragma unroll
        for (int off = 32; off; off >>= 1) s += __shfl_xor(s, off);
        ex[c] = s * rzv * rp[idx];
    }

    bool used[8] = {};
#pragma unroll
    for (int k = 0; k < 3; ++k) {
        float bv = -FLT_MAX; int bi2 = Pn; int bc = 0;
#pragma unroll
        for (int c = 0; c < 8; ++c) {
            if (!used[c] && (ex[c] > bv || (ex[c] == bv && cand[c] < bi2))) {
                bv = ex[c]; bi2 = cand[c]; bc = c;
            }
        }
        used[bc] = true;
        if (lane == 0) {
            oidx[(size_t)row * 3 + k] = (float)bi2;
            oval[(size_t)row * 3 + k] = bv;
        }
    }
}

// ---------------------------------------------------------------------------
// Fallback: 128x128 2-phase kernel (attr failure / smaller ws).
// ---------------------------------------------------------------------------
template <bool FUSE>
__global__ __launch_bounds__(256, 4) void gemm_lds_bf16(
        const unsigned short* __restrict__ Zb,
        const unsigned short* __restrict__ Pb,
        float* __restrict__ sim, uint2* __restrict__ part, int Pn) {
    __shared__ __align__(16) unsigned char SHs[32768];
    uint4* S = (uint4*)SHs;

    int bi = blockIdx.x;
    int mb, nb;
    if (gridDim.x == 16384) {
        int xcd = bi & 7;
        int r = bi >> 3;
        mb = xcd * 8 + (r & 7);
        nb = r >> 3;
    } else {
        nb = bi % (Pn / 128);
        mb = bi / (Pn / 128);
    }
    const int bm = mb * 128, bn = nb * 128;

    const int tid = threadIdx.x;
    const int lane = tid & 63;
    const int wid = tid >> 6;
    const int wr = wid >> 1, wc = wid & 1;
    const int ln15 = lane & 15, hi = lane >> 4;

    const unsigned short* gA[2];
    const unsigned short* gB[2];
    int ldsIdx[2];
#pragma unroll
    for (int q = 0; q < 2; ++q) {
        int flat = q * 256 + tid;
        int row = flat >> 2;
        int c = flat & 3;
        int cg = c ^ (row & 3);
        gA[q] = Zb + (size_t)(bm + row) * D_DIM + cg * 8;
        gB[q] = Pb + (size_t)(bn + row) * D_DIM + cg * 8;
        ldsIdx[q] = flat;
    }

    f32x4 acc[4][4] = {};

#pragma unroll
    for (int q = 0; q < 2; ++q) {
        GLD_LDS16(gA[q], &S[ldsIdx[q]]);
        GLD_LDS16(gB[q], &S[512 + ldsIdx[q]]);
        gA[q] += 32;
        gB[q] += 32;
    }

    int cur = 0;
#pragma unroll 1
    for (int s8 = 0; s8 < 16; ++s8) {
        const int nxt = cur ^ 1;
        if (s8 < 15) {
#pragma unroll
            for (int q = 0; q < 2; ++q) {
                GLD_LDS16(gA[q], &S[nxt * 1024 + ldsIdx[q]]);
                GLD_LDS16(gB[q], &S[nxt * 1024 + 512 + ldsIdx[q]]);
                gA[q] += 32;
                gB[q] += 32;
            }
            asm volatile("s_waitcnt vmcnt(4)" ::: "memory");
        } else {
            asm volatile("s_waitcnt vmcnt(0)" ::: "memory");
        }
        __builtin_amdgcn_s_barrier();
        __builtin_amdgcn_sched_barrier(0);

        const int sb = cur * 1024;
        __builtin_amdgcn_s_setprio(1);
        bf16x8 av[4], bv[4];
#pragma unroll
        for (int t = 0; t < 4; ++t) {
            int arow = wr * 64 + t * 16 + ln15;
            av[t] = __builtin_bit_cast(bf16x8,
                    S[sb + arow * 4 + (hi ^ (arow & 3))]);
            int brow = wc * 64 + t * 16 + ln15;
            bv[t] = __builtin_bit_cast(bf16x8,
                    S[sb + 512 + brow * 4 + (hi ^ (brow & 3))]);
        }
#pragma unroll
        for (int i = 0; i < 4; ++i)
#pragma unroll
            for (int j = 0; j < 4; ++j)
                acc[i][j] = __builtin_amdgcn_mfma_f32_16x16x32_bf16(
                    av[i], bv[j], acc[i][j], 0, 0, 0);
        __builtin_amdgcn_s_setprio(0);
        __builtin_amdgcn_sched_barrier(0);
        __builtin_amdgcn_s_barrier();
        cur = nxt;
    }

#pragma unroll
    for (int i = 0; i < 4; ++i) {
#pragma unroll
        for (int rr = 0; rr < 4; ++rr) {
            int row = bm + wr * 64 + i * 16 + hi * 4 + rr;
#pragma unroll
            for (int j = 0; j < 4; ++j) {
                int col = bn + wc * 64 + j * 16 + ln15;
                sim[(size_t)row * Pn + col] = acc[i][j][rr];
            }
        }
    }

    if constexpr (FUSE) {
        float* T = (float*)SHs;
        uint2* M = (uint2*)(SHs + 17408);
        const int NB = Pn >> 7;
        const int r = tid & 63;
        const int q = tid >> 6;
#pragma unroll 1
        for (int hf = 0; hf < 2; ++hf) {
            float rv[4]; int ri[4];
#pragma unroll
            for (int k = 0; k < 4; ++k) { rv[k] = -FLT_MAX; ri[k] = 0x7FFFFFFF; }
#pragma unroll 1
            for (int ch = 0; ch < 2; ++ch) {
                __syncthreads();
                if (wr == hf && wc == ch) {
#pragma unroll
                    for (int i = 0; i < 4; ++i)
#pragma unroll
                        for (int j = 0; j < 4; ++j)
                            *(f32x4*)&T[(j * 16 + ln15) * 68 + i * 16 + hi * 4]
                                = acc[i][j];
                }
                __syncthreads();
                float tv[4]; int ti[4];
#pragma unroll
                for (int k = 0; k < 4; ++k) { tv[k] = -FLT_MAX; ti[k] = 0x7FFFFFFF; }
#pragma unroll
                for (int c4 = 0; c4 < 16; c4 += 4) {
                    float e0 = T[(q * 16 + c4 + 0) * 68 + r];
                    float e1 = T[(q * 16 + c4 + 1) * 68 + r];
                    float e2 = T[(q * 16 + c4 + 2) * 68 + r];
                    float e3 = T[(q * 16 + c4 + 3) * 68 + r];
                    float mg = fmaxf(fmaxf(e0, e1), fmaxf(e2, e3));
                    if (mg > tv[3]) {
                        int cb = bn + ch * 64 + q * 16 + c4;
                        INS4(e0, cb + 0, tv, ti);
                        INS4(e1, cb + 1, tv, ti);
                        INS4(e2, cb + 2, tv, ti);
                        INS4(e3, cb + 3, tv, ti);
                    }
                }
#pragma unroll
                for (int k = 0; k < 4; ++k)
                    M[q * 256 + k * 64 + r] =
                        make_uint2(__builtin_bit_cast(uint32_t, tv[k]), (uint32_t)ti[k]);
                __syncthreads();
                if (tid < 64) {
#pragma unroll
                    for (int qq = 0; qq < 4; ++qq)
#pragma unroll
                        for (int k = 0; k < 4; ++k) {
                            uint2 u = M[qq * 256 + k * 64 + tid];
                            float val = __builtin_bit_cast(float, u.x);
                            INS4(val, (int)u.y, rv, ri);
                        }
                }
            }
            if (tid < 64) {
                size_t o = ((size_t)(bm + hf * 64 + tid) * NB + nb) * 4;
#pragma unroll
                for (int k = 0; k < 4; ++k)
                    part[o + k] =
                        make_uint2(__builtin_bit_cast(uint32_t, rv[k]), (uint32_t)ri[k]);
            }
        }
    }
}

// ---------------------------------------------------------------------------
// Deep fallbacks: f32-input GEMM + full-sim topk (tiny ws).
// ---------------------------------------------------------------------------
__global__ __launch_bounds__(256) void rnorm_kernel(const float* __restrict__ X,
                                                    float* __restrict__ r, int R) {
    int row = blockIdx.x * 4 + (threadIdx.x >> 6);
    if (row >= R) return;
    int lane = threadIdx.x & 63;
    const float* x = X + (size_t)row * D_DIM;
    float s = 0.f;
#pragma unroll
    for (int t = 0; t < 2; ++t) {
        float4 v = *(const float4*)(x + (t * 64 + lane) * 4);
        s += v.x * v.x + v.y * v.y + v.z * v.z + v.w * v.w;
    }
#pragma unroll
    for (int off = 32; off; off >>= 1) s += __shfl_xor(s, off);
    if (lane == 0) r[row] = 1.0f / fmaxf(sqrtf(s), 1e-12f);
}

__global__ __launch_bounds__(256, 2) void gemm_bf16_sim(const float* __restrict__ Z,
        const float* __restrict__ Pm, const float* __restrict__ rz,
        const float* __restrict__ rp, float* __restrict__ sim, int Pn) {
    __shared__ uint4 As16[1024];
    __shared__ uint4 Bs16[1024];
    int bi = blockIdx.x;
    int nb = bi % (Pn / 128);
    int mb = bi / (Pn / 128);
    const int bm = mb * 128, bn = nb * 128;
    const int tid = threadIdx.x;
    const int srow = tid >> 1;
    const int half = tid & 1;
    const float* aP = Z  + (size_t)(bm + srow) * D_DIM + half * 32;
    const float* bP = Pm + (size_t)(bn + srow) * D_DIM + half * 32;
    const int lane = tid & 63;
    const int wid = tid >> 6;
    const int wr = wid >> 1, wc = wid & 1;
    const int ln15 = lane & 15, hi = lane >> 4;
    f32x4 acc[4][4] = {};
    float4 f[8], g[8];
#pragma unroll
    for (int q = 0; q < 8; ++q) {
        f[q] = *(const float4*)(aP + q * 4);
        g[q] = *(const float4*)(bP + q * 4);
    }
#pragma unroll 1
    for (int s = 0; s < 8; ++s) {
#pragma unroll
        for (int q8 = 0; q8 < 4; ++q8) {
            uint4 wa, wb;
            wa.x = pk_bf16(f[2*q8].x,   f[2*q8].y);
            wa.y = pk_bf16(f[2*q8].z,   f[2*q8].w);
            wa.z = pk_bf16(f[2*q8+1].x, f[2*q8+1].y);
            wa.w = pk_bf16(f[2*q8+1].z, f[2*q8+1].w);
            wb.x = pk_bf16(g[2*q8].x,   g[2*q8].y);
            wb.y = pk_bf16(g[2*q8].z,   g[2*q8].w);
            wb.z = pk_bf16(g[2*q8+1].x, g[2*q8+1].y);
            wb.w = pk_bf16(g[2*q8+1].z, g[2*q8+1].w);
            int colByte = half * 64 + q8 * 16;
            int idx = srow * 8 + ((colByte ^ ((srow & 7) << 4)) >> 4);
            As16[idx] = wa;
            Bs16[idx] = wb;
        }
        __syncthreads();
        if (s < 7) {
            int k0 = (s + 1) * 64;
#pragma unroll
            for (int q = 0; q < 8; ++q) {
                f[q] = *(const float4*)(aP + k0 + q * 4);
                g[q] = *(const float4*)(bP + k0 + q * 4);
            }
        }
#pragma unroll
        for (int kk = 0; kk < 2; ++kk) {
            bf16x8 av[4], bv[4];
            const int cb = kk * 64 + hi * 16;
#pragma unroll
            for (int t = 0; t < 4; ++t) {
                int arow = wr * 64 + t * 16 + ln15;
                av[t] = __builtin_bit_cast(bf16x8,
                        As16[arow * 8 + ((cb ^ ((arow & 7) << 4)) >> 4)]);
                int brow = wc * 64 + t * 16 + ln15;
                bv[t] = __builtin_bit_cast(bf16x8,
                        Bs16[brow * 8 + ((cb ^ ((brow & 7) << 4)) >> 4)]);
            }
#pragma unroll
            for (int i = 0; i < 4; ++i)
#pragma unroll
                for (int j = 0; j < 4; ++j)
                    acc[i][j] = __builtin_amdgcn_mfma_f32_16x16x32_bf16(
                        av[i], bv[j], acc[i][j], 0, 0, 0);
        }
        __syncthreads();
    }
    float rpv[4];
#pragma unroll
    for (int j = 0; j < 4; ++j) rpv[j] = rp[bn + wc * 64 + j * 16 + ln15];
#pragma unroll
    for (int i = 0; i < 4; ++i) {
#pragma unroll
        for (int rr = 0; rr < 4; ++rr) {
            int row = bm + wr * 64 + i * 16 + hi * 4 + rr;
            float rzv = rz[row];
#pragma unroll
            for (int j = 0; j < 4; ++j) {
                int col = bn + wc * 64 + j * 16 + ln15;
                sim[(size_t)row * Pn + col] = acc[i][j][rr] * rzv * rpv[j];
            }
        }
    }
}

__global__ __launch_bounds__(256) void topk_refine(const float* __restrict__ sim,
        const float* __restrict__ Z, const float* __restrict__ Pm,
        const float* __restrict__ rz, const float* __restrict__ rp,
        float* __restrict__ oidx, float* __restrict__ oval, int Pn) {
    int row = blockIdx.x * 4 + (threadIdx.x >> 6);
    int lane = threadIdx.x & 63;
    const float* rptr = sim + (size_t)row * Pn;

    float v[8]; int ix[8];
#pragma unroll
    for (int j = 0; j < 8; ++j) { v[j] = -FLT_MAX; ix[j] = -1; }

    const int iters = Pn >> 8;
    for (int t = 0; t < iters; ++t) {
        int base = t * 256 + lane * 4;
        float4 q = *(const float4*)(rptr + base);
        float vals[4] = {q.x, q.y, q.z, q.w};
#pragma unroll
        for (int e = 0; e < 4; ++e) {
            float val = vals[e];
            if (val > v[7]) {
                int idx = base + e;
                int pos = 7;
#pragma unroll
                for (int j = 6; j >= 0; --j) {
                    if (val > v[j]) { v[j+1] = v[j]; ix[j+1] = ix[j]; pos = j; }
                }
                v[pos] = val; ix[pos] = idx;
            }
        }
    }

    int cand[8];
#pragma unroll
    for (int k = 0; k < 8; ++k) {
        float bv = v[0]; int bi2 = ix[0];
#pragma unroll
        for (int off = 32; off; off >>= 1) {
            float ov = __shfl_xor(bv, off);
            int oi = __shfl_xor(bi2, off);
            if (ov > bv || (ov == bv && oi >= 0 && (unsigned)oi < (unsigned)bi2)) {
                bv = ov; bi2 = oi;
            }
        }
        cand[k] = bi2;
        if (bi2 == ix[0]) {
#pragma unroll
            for (int j = 0; j < 7; ++j) { v[j] = v[j+1]; ix[j] = ix[j+1]; }
            v[7] = -FLT_MAX; ix[7] = -1;
        }
    }

    float zv[8];
    const float* zrow = Z + (size_t)row * D_DIM + lane * 8;
#pragma unroll
    for (int j = 0; j < 8; ++j) zv[j] = zrow[j];
    float rzv = rz[row];

    float ex[8];
#pragma unroll
    for (int c = 0; c < 8; ++c) {
        int idx = cand[c];
        const float* prow = Pm + (size_t)idx * D_DIM + lane * 8;
        float s = 0.f;
#pragma unroll
        for (int j = 0; j < 8; ++j) s += zv[j] * prow[j];
#pragma unroll
        for (int off = 32; off; off >>= 1) s += __shfl_xor(s, off);
        ex[c] = s * rzv * rp[idx];
    }

    bool used[8] = {};
#pragma unroll
    for (int k = 0; k < 3; ++k) {
        float bv = -FLT_MAX; int bi2 = Pn; int bc = 0;
#pragma unroll
        for (int c = 0; c < 8; ++c) {
            if (!used[c] && (ex[c] > bv || (ex[c] == bv && cand[c] < bi2))) {
                bv = ex[c]; bi2 = cand[c]; bc = c;
            }
        }
        used[bc] = true;
        if (lane == 0) {
            oidx[(size_t)row * 3 + k] = (float)bi2;
            oval[(size_t)row * 3 + k] = bv;
        }
    }
}

extern "C" void kernel_launch(void* const* d_in, const int* in_sizes, int n_in,
                              void* d_out, int out_size, void* d_ws, size_t ws_size,
                              hipStream_t stream) {
    const float* Z  = (const float*)d_in[0];   // [B, 512]
    const float* Pm = (const float*)d_in[1];   // [P, 512]
    const int B  = in_sizes[0] / D_DIM;        // 8192
    const int Pn = in_sizes[1] / D_DIM;        // 32768

    float* sim  = (float*)d_out;
    float* oidx = sim + (size_t)B * Pn;
    float* oval = oidx + (size_t)B * 3;

    float* rz = (float*)d_ws;
    float* rp = rz + B;
    unsigned short* Zb = (unsigned short*)(rp + Pn);
    unsigned short* Pb = Zb + (size_t)B * D_DIM;
    uint2* part = (uint2*)(Pb + (size_t)Pn * D_DIM);

    const size_t need_bf16 = (size_t)(B + Pn) * 4 + (size_t)(B + Pn) * D_DIM * 2;
    const size_t need256 = need_bf16 + (size_t)B * (Pn >> 8) * 4 * sizeof(uint2);
    const size_t need128 = need_bf16 + (size_t)B * (Pn >> 7) * 4 * sizeof(uint2);

    bool big = false;
    if ((B & 255) == 0 && (Pn & 255) == 0 && ws_size >= need256) {
        big = (hipFuncSetAttribute((const void*)gemm256_fused,
                   hipFuncAttributeMaxDynamicSharedMemorySize,
                   131072) == hipSuccess);
    }

    if (big) {
        convert_norm_kernel<<<B / 4, 256, 0, stream>>>(Z, Zb, rz, B);
        convert_norm_kernel<<<Pn / 4, 256, 0, stream>>>(Pm, Pb, rp, Pn);
        gemm256_fused<<<(B / 256) * (Pn / 256), 512, 131072, stream>>>(
            Zb, Pb, sim, part, Pn);
        topk_reduce<<<B / 4, 256, 0, stream>>>(part, Z, Pm, rz, rp,
                                               oidx, oval, Pn, Pn >> 8);
    } else if (ws_size >= need128) {
        convert_norm_kernel<<<B / 4, 256, 0, stream>>>(Z, Zb, rz, B);
        convert_norm_kernel<<<Pn / 4, 256, 0, stream>>>(Pm, Pb, rp, Pn);
        gemm_lds_bf16<true><<<(B / 128) * (Pn / 128), 256, 0, stream>>>(
            Zb, Pb, sim, part, Pn);
        topk_reduce<<<B / 4, 256, 0, stream>>>(part, Z, Pm, rz, rp,
                                               oidx, oval, Pn, Pn >> 7);
    } else if (ws_size >= need_bf16) {
        convert_norm_kernel<<<B / 4, 256, 0, stream>>>(Z, Zb, rz, B);
        convert_norm_kernel<<<Pn / 4, 256, 0, stream>>>(Pm, Pb, rp, Pn);
        gemm_lds_bf16<false><<<(B / 128) * (Pn / 128), 256, 0, stream>>>(
            Zb, Pb, sim, nullptr, Pn);
        topk_refine<<<B / 4, 256, 0, stream>>>(sim, Z, Pm, rz, rp, oidx, oval, Pn);
    } else {
        rnorm_kernel<<<B / 4, 256, 0, stream>>>(Z, rz, B);
        rnorm_kernel<<<Pn / 4, 256, 0, stream>>>(Pm, rp, Pn);
        gemm_bf16_sim<<<(B / 128) * (Pn / 128), 256, 0, stream>>>(
            Z, Pm, rz, rp, sim, Pn);
        topk_refine<<<B / 4, 256, 0, stream>>>(sim, Z, Pm, rz, rp, oidx, oval, Pn);
    }
}

// Round 15
// 628.537 us; speedup vs baseline: 1.0860x; 1.0113x over previous
//
#include <hip/hip_runtime.h>
#include <float.h>
#include <stdint.h>

#define D_DIM 512

typedef __attribute__((ext_vector_type(8))) short bf16x8;
typedef __attribute__((ext_vector_type(4))) float f32x4;

// async global->LDS, 16B per lane (linear LDS dest: wave base + lane*16)
#define GLD_LDS16(g, l)                                              \
    __builtin_amdgcn_global_load_lds(                                \
        (const __attribute__((address_space(1))) void*)(g),          \
        (__attribute__((address_space(3))) void*)(l), 16, 0, 0)

// round-half-up f32->bf16, pack two into one u32
__device__ __forceinline__ uint32_t pk_bf16(float a, float b) {
    uint32_t ua = __builtin_bit_cast(uint32_t, a) + 0x8000u;
    uint32_t ub = __builtin_bit_cast(uint32_t, b) + 0x8000u;
    return (ua >> 16) | (ub & 0xFFFF0000u);
}

// sorted-desc top-4 insert, static indices only
#define INS4(val, idx, tv, ti)                                        \
    if ((val) > tv[3]) {                                              \
        int p_ = 3;                                                   \
        if ((val) > tv[2]) { tv[3] = tv[2]; ti[3] = ti[2]; p_ = 2; }  \
        if ((val) > tv[1]) { tv[2] = tv[1]; ti[2] = ti[1]; p_ = 1; }  \
        if ((val) > tv[0]) { tv[1] = tv[0]; ti[1] = ti[0]; p_ = 0; }  \
        tv[p_] = (val); ti[p_] = (idx);                               \
    }

// ---------------------------------------------------------------------------
// Per-row: r[row] = 1/max(||X[row]||,eps); Xb[row,:] = bf16(X[row,:] * r).
// ---------------------------------------------------------------------------
__global__ __launch_bounds__(256) void convert_norm_kernel(
        const float* __restrict__ X, unsigned short* __restrict__ Xb,
        float* __restrict__ r, int R) {
    int row = blockIdx.x * 4 + (threadIdx.x >> 6);
    if (row >= R) return;
    int lane = threadIdx.x & 63;
    const float* x = X + (size_t)row * D_DIM + lane * 8;
    float4 f0 = *(const float4*)(x);
    float4 f1 = *(const float4*)(x + 4);
    float s = f0.x*f0.x + f0.y*f0.y + f0.z*f0.z + f0.w*f0.w
            + f1.x*f1.x + f1.y*f1.y + f1.z*f1.z + f1.w*f1.w;
#pragma unroll
    for (int off = 32; off; off >>= 1) s += __shfl_xor(s, off);
    float rv = 1.0f / fmaxf(sqrtf(s), 1e-12f);
    if (lane == 0) r[row] = rv;
    uint4 w;
    w.x = pk_bf16(f0.x * rv, f0.y * rv);
    w.y = pk_bf16(f0.z * rv, f0.w * rv);
    w.z = pk_bf16(f1.x * rv, f1.y * rv);
    w.w = pk_bf16(f1.z * rv, f1.w * rv);
    *(uint4*)(Xb + (size_t)row * D_DIM + lane * 8) = w;
}

// ---------------------------------------------------------------------------
// 256x256 8-wave bf16 GEMM, r15: r14 overlapped-read pipeline, minus the
// forced lgkmcnt(0) drain (prefetch reads complete under the barrier; the
// compiler inserts precise lgkmcnt(N) before the next interval's MFMA use).
// BK=32 subtiles (16), 4 LDS buffers (128KB dynamic), 2-way swizzle.
// Interval s: {ds_read subtile s+1 -> other reg set || ISSUE(s+3)}
//   -> MFMA(s) -> counted vmcnt (certify s+2) -> sched_barrier -> barrier.
// Fused epilogue: row-major T2, vector scan, contiguous nontemporal stores.
// ---------------------------------------------------------------------------
__global__ __launch_bounds__(512, 2) void gemm256_fused(
        const unsigned short* __restrict__ Zb,
        const unsigned short* __restrict__ Pb,
        float* __restrict__ sim, uint2* __restrict__ part, int Pn) {
    extern __shared__ __align__(16) unsigned char SH[];
    uint4* S = (uint4*)SH;   // buf q: q*2048 + (A: 0..1023 | B: 1024..2047)

    int bi = blockIdx.x;
    int mb, nb;
    if (gridDim.x == 4096) {             // XCD chunk map (B=8192, P=32768)
        int xcd = bi & 7, r = bi >> 3;
        mb = xcd * 4 + (r & 3);          // 0..31
        nb = r >> 2;                     // 0..127
    } else {
        int nt = Pn >> 8;
        nb = bi % nt; mb = bi / nt;
    }
    const int bm = mb << 8, bn = nb << 8;

    const int tid = threadIdx.x;
    const int lane = tid & 63;
    const int wid = tid >> 6;
    const int wr = wid >> 2;             // 0..1
    const int wc = wid & 3;              // 0..3
    const int ln15 = lane & 15, hi = lane >> 4;

    // ---- staging addressing: per thread 2 chunks for A and 2 for B ----
    const int f0 = tid, f1 = 512 + tid;
    // LDS slot (row,c) holds global chunk c ^ ((row>>1)&3); row=f>>2, c=f&3
    const int cg0 = (f0 & 3) ^ ((f0 >> 3) & 3);
    const int cg1 = (f1 & 3) ^ ((f1 >> 3) & 3);
    const int r0 = f0 >> 2, r1 = f1 >> 2;

    const unsigned short* pA0 = Zb + (size_t)(bm + r0) * D_DIM + cg0 * 8;
    const unsigned short* pA1 = Zb + (size_t)(bm + r1) * D_DIM + cg1 * 8;
    const unsigned short* pB0 = Pb + (size_t)(bn + r0) * D_DIM + cg0 * 8;
    const unsigned short* pB1 = Pb + (size_t)(bn + r1) * D_DIM + cg1 * 8;

#define ISSUE(qb)                                                    \
    do {                                                             \
        GLD_LDS16(pA0, &S[(qb) * 2048 + f0]);                        \
        GLD_LDS16(pA1, &S[(qb) * 2048 + f1]);                        \
        GLD_LDS16(pB0, &S[(qb) * 2048 + 1024 + f0]);                 \
        GLD_LDS16(pB1, &S[(qb) * 2048 + 1024 + f1]);                 \
        pA0 += 32; pA1 += 32; pB0 += 32; pB1 += 32;                  \
    } while (0)

    // ---- fragment read offsets: chunk = hi ^ ((row>>1)&3); for all frag
    // rows, (row>>1)&3 == (ln15>>1)&3 (row = 16k + ln15, 16k mult of 8) ----
    const int sw = hi ^ ((ln15 >> 1) & 3);
    int aOff[8], bOff[4];
#pragma unroll
    for (int m = 0; m < 8; ++m) aOff[m] = (wr * 128 + m * 16 + ln15) * 4 + sw;
#pragma unroll
    for (int n = 0; n < 4; ++n) bOff[n] = 1024 + (wc * 64 + n * 16 + ln15) * 4 + sw;

    f32x4 acc[8][4] = {};
    bf16x8 Xa[8], Xb4[4], Ya[8], Yb4[4];

    // ---- prologue: stage 0,1,2; certify 0 AND 1; read subtile 0 -> X ----
    ISSUE(0); ISSUE(1); ISSUE(2);
    asm volatile("s_waitcnt vmcnt(4)" ::: "memory");
    __builtin_amdgcn_s_barrier();
    {
#pragma unroll
        for (int mi = 0; mi < 8; ++mi)
            Xa[mi] = __builtin_bit_cast(bf16x8, S[aOff[mi]]);
#pragma unroll
        for (int ni = 0; ni < 4; ++ni)
            Xb4[ni] = __builtin_bit_cast(bf16x8, S[bOff[ni]]);
    }

#pragma unroll 1
    for (int s2 = 0; s2 < 8; ++s2) {
        const int s0 = s2 * 2;
        // ---- interval s0: prefetch Y <- subtile s0+1; MFMA on X ----
        {
#pragma unroll
            for (int mi = 0; mi < 8; ++mi)
                Ya[mi] = __builtin_bit_cast(bf16x8,
                             S[((s0 + 1) & 3) * 2048 + aOff[mi]]);
#pragma unroll
            for (int ni = 0; ni < 4; ++ni)
                Yb4[ni] = __builtin_bit_cast(bf16x8,
                             S[((s0 + 1) & 3) * 2048 + bOff[ni]]);
        }
        if (s0 <= 12) ISSUE((s0 + 3) & 3);
        __builtin_amdgcn_s_setprio(1);
#pragma unroll
        for (int mi = 0; mi < 8; ++mi)
#pragma unroll
            for (int ni = 0; ni < 4; ++ni)
                acc[mi][ni] = __builtin_amdgcn_mfma_f32_16x16x32_bf16(
                    Xa[mi], Xb4[ni], acc[mi][ni], 0, 0, 0);
        __builtin_amdgcn_s_setprio(0);
        if (s0 <= 12) asm volatile("s_waitcnt vmcnt(4)" ::: "memory");
        else          asm volatile("s_waitcnt vmcnt(0)" ::: "memory");
        __builtin_amdgcn_sched_barrier(0);
        __builtin_amdgcn_s_barrier();

        // ---- interval s1=s0+1: prefetch X <- subtile s1+1; MFMA on Y ----
        const int s1 = s0 + 1;
        if (s1 < 15) {
#pragma unroll
            for (int mi = 0; mi < 8; ++mi)
                Xa[mi] = __builtin_bit_cast(bf16x8,
                             S[((s1 + 1) & 3) * 2048 + aOff[mi]]);
#pragma unroll
            for (int ni = 0; ni < 4; ++ni)
                Xb4[ni] = __builtin_bit_cast(bf16x8,
                             S[((s1 + 1) & 3) * 2048 + bOff[ni]]);
        }
        if (s1 <= 12) ISSUE((s1 + 3) & 3);
        __builtin_amdgcn_s_setprio(1);
#pragma unroll
        for (int mi = 0; mi < 8; ++mi)
#pragma unroll
            for (int ni = 0; ni < 4; ++ni)
                acc[mi][ni] = __builtin_amdgcn_mfma_f32_16x16x32_bf16(
                    Ya[mi], Yb4[ni], acc[mi][ni], 0, 0, 0);
        __builtin_amdgcn_s_setprio(0);
        if (s1 < 15) {
            if (s1 <= 12) asm volatile("s_waitcnt vmcnt(4)" ::: "memory");
            else          asm volatile("s_waitcnt vmcnt(0)" ::: "memory");
            __builtin_amdgcn_sched_barrier(0);
            __builtin_amdgcn_s_barrier();
        }
    }
#undef ISSUE

    // ---- fused epilogue: row-major T2, vector scan, contiguous stores ----
    float* T2 = (float*)SH;              // [128 rows][136] f32 = 69632 B
    const int NB = Pn >> 8;
    const int r = tid >> 2;              // 0..127 (scan row)
    const int g = tid & 3;               // scan col group
    const int srl = lane >> 5;           // store: row-within-pair 0..1
    const int sc4 = (lane & 31) * 4;     // store: col (x4 floats)
#pragma unroll 1
    for (int hf = 0; hf < 2; ++hf) {
        float tv[4]; int ti[4];
#pragma unroll
        for (int k = 0; k < 4; ++k) { tv[k] = -FLT_MAX; ti[k] = 0x7FFFFFFF; }
#pragma unroll 1
        for (int ch = 0; ch < 2; ++ch) {
            __syncthreads();             // T2 free (prev phase readers done)
            if (wr == hf && (wc >> 1) == ch) {
#pragma unroll
                for (int m = 0; m < 8; ++m)
#pragma unroll
                    for (int n = 0; n < 4; ++n) {
                        int col = (wc & 1) * 64 + n * 16 + ln15;
#pragma unroll
                        for (int rr = 0; rr < 4; ++rr)
                            T2[(m * 16 + hi * 4 + rr) * 136 + col]
                                = acc[m][n][rr];
                    }
            }
            __syncthreads();
            const int colBase = bn + ch * 128;
            // scan: thread (r, g): 8 vector reads + gated INS4
#pragma unroll
            for (int j = 0; j < 8; ++j) {
                const int c0 = j * 16 + g * 4;
                f32x4 e = *(const f32x4*)&T2[r * 136 + c0];
                float mg = fmaxf(fmaxf(e[0], e[1]), fmaxf(e[2], e[3]));
                if (mg > tv[3]) {
                    INS4(e[0], colBase + c0 + 0, tv, ti);
                    INS4(e[1], colBase + c0 + 1, tv, ti);
                    INS4(e[2], colBase + c0 + 2, tv, ti);
                    INS4(e[3], colBase + c0 + 3, tv, ti);
                }
            }
            // contiguous store: wave wid -> rows wid*16..+15, 2 rows/instr
#pragma unroll
            for (int it = 0; it < 8; ++it) {
                int rowL = wid * 16 + it * 2 + srl;
                f32x4 v = *(const f32x4*)&T2[rowL * 136 + sc4];
                __builtin_nontemporal_store(v,
                    (f32x4*)&sim[(size_t)(bm + hf * 128 + rowL) * Pn
                                 + colBase + sc4]);
            }
        }
        // merge top-4 across the 4-lane col groups (lanes 4r..4r+3)
#pragma unroll
        for (int st = 1; st <= 2; st <<= 1) {
            float ov0 = __shfl_xor(tv[0], st), ov1 = __shfl_xor(tv[1], st);
            float ov2 = __shfl_xor(tv[2], st), ov3 = __shfl_xor(tv[3], st);
            int oi0 = __shfl_xor(ti[0], st), oi1 = __shfl_xor(ti[1], st);
            int oi2 = __shfl_xor(ti[2], st), oi3 = __shfl_xor(ti[3], st);
            INS4(ov0, oi0, tv, ti);
            INS4(ov1, oi1, tv, ti);
            INS4(ov2, oi2, tv, ti);
            INS4(ov3, oi3, tv, ti);
        }
        if (g == 0) {
            size_t o = ((size_t)(bm + hf * 128 + r) * NB + nb) * 4;
#pragma unroll
            for (int k = 0; k < 4; ++k)
                part[o + k] =
                    make_uint2(__builtin_bit_cast(uint32_t, tv[k]), (uint32_t)ti[k]);
        }
    }
}

// ---------------------------------------------------------------------------
// Reduce partial candidates (NB*4 per row) -> noisy top-8 -> exact f32
// rerank -> top-3. One wave per row.
// ---------------------------------------------------------------------------
__global__ __launch_bounds__(256) void topk_reduce(const uint2* __restrict__ part,
        const float* __restrict__ Z, const float* __restrict__ Pm,
        const float* __restrict__ rz, const float* __restrict__ rp,
        float* __restrict__ oidx, float* __restrict__ oval, int Pn, int NB) {
    int row = blockIdx.x * 4 + (threadIdx.x >> 6);
    int lane = threadIdx.x & 63;
    const uint2* pr = part + (size_t)row * NB * 4;

    float v[8]; int ix[8];
#pragma unroll
    for (int j = 0; j < 8; ++j) { v[j] = -FLT_MAX; ix[j] = -1; }

    const int total = NB * 4;
    for (int c = lane; c < total; c += 64) {
        uint2 u = pr[c];
        float val = __builtin_bit_cast(float, u.x);
        if (val > v[7]) {
            int idx = (int)u.y;
            int pos = 7;
#pragma unroll
            for (int j = 6; j >= 0; --j) {
                if (val > v[j]) { v[j+1] = v[j]; ix[j+1] = ix[j]; pos = j; }
            }
            v[pos] = val; ix[pos] = idx;
        }
    }

    int cand[8];
#pragma unroll
    for (int k = 0; k < 8; ++k) {
        float bv = v[0]; int bi2 = ix[0];
#pragma unroll
        for (int off = 32; off; off >>= 1) {
            float ov = __shfl_xor(bv, off);
            int oi = __shfl_xor(bi2, off);
            if (ov > bv || (ov == bv && oi >= 0 && (unsigned)oi < (unsigned)bi2)) {
                bv = ov; bi2 = oi;
            }
        }
        cand[k] = bi2;
        if (bi2 == ix[0]) {
#pragma unroll
            for (int j = 0; j < 7; ++j) { v[j] = v[j+1]; ix[j] = ix[j+1]; }
            v[7] = -FLT_MAX; ix[7] = -1;
        }
    }

    // exact f32 recompute of the 8 candidate similarities
    float zv[8];
    const float* zrow = Z + (size_t)row * D_DIM + lane * 8;
#pragma unroll
    for (int j = 0; j < 8; ++j) zv[j] = zrow[j];
    float rzv = rz[row];

    float ex[8];
#pragma unroll
    for (int c = 0; c < 8; ++c) {
        int idx = cand[c];
        const float* prow = Pm + (size_t)idx * D_DIM + lane * 8;
        float s = 0.f;
#pragma unroll
        for (int j = 0; j < 8; ++j) s += zv[j] * prow[j];
#pragma unroll
        for (int off = 32; off; off >>= 1) s += __shfl_xor(s, off);
        ex[c] = s * rzv * rp[idx];
    }

    bool used[8] = {};
#pragma unroll
    for (int k = 0; k < 3; ++k) {
        float bv = -FLT_MAX; int bi2 = Pn; int bc = 0;
#pragma unroll
        for (int c = 0; c < 8; ++c) {
            if (!used[c] && (ex[c] > bv || (ex[c] == bv && cand[c] < bi2))) {
                bv = ex[c]; bi2 = cand[c]; bc = c;
            }
        }
        used[bc] = true;
        if (lane == 0) {
            oidx[(size_t)row * 3 + k] = (float)bi2;
            oval[(size_t)row * 3 + k] = bv;
        }
    }
}

// ---------------------------------------------------------------------------
// Fallback: 128x128 2-phase kernel (attr failure / smaller ws).
// ---------------------------------------------------------------------------
template <bool FUSE>
__global__ __launch_bounds__(256, 4) void gemm_lds_bf16(
        const unsigned short* __restrict__ Zb,
        const unsigned short* __restrict__ Pb,
        float* __restrict__ sim, uint2* __restrict__ part, int Pn) {
    __shared__ __align__(16) unsigned char SHs[32768];
    uint4* S = (uint4*)SHs;

    int bi = blockIdx.x;
    int mb, nb;
    if (gridDim.x == 16384) {
        int xcd = bi & 7;
        int r = bi >> 3;
        mb = xcd * 8 + (r & 7);
        nb = r >> 3;
    } else {
        nb = bi % (Pn / 128);
        mb = bi / (Pn / 128);
    }
    const int bm = mb * 128, bn = nb * 128;

    const int tid = threadIdx.x;
    const int lane = tid & 63;
    const int wid = tid >> 6;
    const int wr = wid >> 1, wc = wid & 1;
    const int ln15 = lane & 15, hi = lane >> 4;

    const unsigned short* gA[2];
    const unsigned short* gB[2];
    int ldsIdx[2];
#pragma unroll
    for (int q = 0; q < 2; ++q) {
        int flat = q * 256 + tid;
        int row = flat >> 2;
        int c = flat & 3;
        int cg = c ^ (row & 3);
        gA[q] = Zb + (size_t)(bm + row) * D_DIM + cg * 8;
        gB[q] = Pb + (size_t)(bn + row) * D_DIM + cg * 8;
        ldsIdx[q] = flat;
    }

    f32x4 acc[4][4] = {};

#pragma unroll
    for (int q = 0; q < 2; ++q) {
        GLD_LDS16(gA[q], &S[ldsIdx[q]]);
        GLD_LDS16(gB[q], &S[512 + ldsIdx[q]]);
        gA[q] += 32;
        gB[q] += 32;
    }

    int cur = 0;
#pragma unroll 1
    for (int s8 = 0; s8 < 16; ++s8) {
        const int nxt = cur ^ 1;
        if (s8 < 15) {
#pragma unroll
            for (int q = 0; q < 2; ++q) {
                GLD_LDS16(gA[q], &S[nxt * 1024 + ldsIdx[q]]);
                GLD_LDS16(gB[q], &S[nxt * 1024 + 512 + ldsIdx[q]]);
                gA[q] += 32;
                gB[q] += 32;
            }
            asm volatile("s_waitcnt vmcnt(4)" ::: "memory");
        } else {
            asm volatile("s_waitcnt vmcnt(0)" ::: "memory");
        }
        __builtin_amdgcn_s_barrier();
        __builtin_amdgcn_sched_barrier(0);

        const int sb = cur * 1024;
        __builtin_amdgcn_s_setprio(1);
        bf16x8 av[4], bv[4];
#pragma unroll
        for (int t = 0; t < 4; ++t) {
            int arow = wr * 64 + t * 16 + ln15;
            av[t] = __builtin_bit_cast(bf16x8,
                    S[sb + arow * 4 + (hi ^ (arow & 3))]);
            int brow = wc * 64 + t * 16 + ln15;
            bv[t] = __builtin_bit_cast(bf16x8,
                    S[sb + 512 + brow * 4 + (hi ^ (brow & 3))]);
        }
#pragma unroll
        for (int i = 0; i < 4; ++i)
#pragma unroll
            for (int j = 0; j < 4; ++j)
                acc[i][j] = __builtin_amdgcn_mfma_f32_16x16x32_bf16(
                    av[i], bv[j], acc[i][j], 0, 0, 0);
        __builtin_amdgcn_s_setprio(0);
        __builtin_amdgcn_sched_barrier(0);
        __builtin_amdgcn_s_barrier();
        cur = nxt;
    }

#pragma unroll
    for (int i = 0; i < 4; ++i) {
#pragma unroll
        for (int rr = 0; rr < 4; ++rr) {
            int row = bm + wr * 64 + i * 16 + hi * 4 + rr;
#pragma unroll
            for (int j = 0; j < 4; ++j) {
                int col = bn + wc * 64 + j * 16 + ln15;
                sim[(size_t)row * Pn + col] = acc[i][j][rr];
            }
        }
    }

    if constexpr (FUSE) {
        float* T = (float*)SHs;
        uint2* M = (uint2*)(SHs + 17408);
        const int NB = Pn >> 7;
        const int r = tid & 63;
        const int q = tid >> 6;
#pragma unroll 1
        for (int hf = 0; hf < 2; ++hf) {
            float rv[4]; int ri[4];
#pragma unroll
            for (int k = 0; k < 4; ++k) { rv[k] = -FLT_MAX; ri[k] = 0x7FFFFFFF; }
#pragma unroll 1
            for (int ch = 0; ch < 2; ++ch) {
                __syncthreads();
                if (wr == hf && wc == ch) {
#pragma unroll
                    for (int i = 0; i < 4; ++i)
#pragma unroll
                        for (int j = 0; j < 4; ++j)
                            *(f32x4*)&T[(j * 16 + ln15) * 68 + i * 16 + hi * 4]
                                = acc[i][j];
                }
                __syncthreads();
                float tv[4]; int ti[4];
#pragma unroll
                for (int k = 0; k < 4; ++k) { tv[k] = -FLT_MAX; ti[k] = 0x7FFFFFFF; }
#pragma unroll
                for (int c4 = 0; c4 < 16; c4 += 4) {
                    float e0 = T[(q * 16 + c4 + 0) * 68 + r];
                    float e1 = T[(q * 16 + c4 + 1) * 68 + r];
                    float e2 = T[(q * 16 + c4 + 2) * 68 + r];
                    float e3 = T[(q * 16 + c4 + 3) * 68 + r];
                    float mg = fmaxf(fmaxf(e0, e1), fmaxf(e2, e3));
                    if (mg > tv[3]) {
                        int cb = bn + ch * 64 + q * 16 + c4;
                        INS4(e0, cb + 0, tv, ti);
                        INS4(e1, cb + 1, tv, ti);
                        INS4(e2, cb + 2, tv, ti);
                        INS4(e3, cb + 3, tv, ti);
                    }
                }
#pragma unroll
                for (int k = 0; k < 4; ++k)
                    M[q * 256 + k * 64 + r] =
                        make_uint2(__builtin_bit_cast(uint32_t, tv[k]), (uint32_t)ti[k]);
                __syncthreads();
                if (tid < 64) {
#pragma unroll
                    for (int qq = 0; qq < 4; ++qq)
#pragma unroll
                        for (int k = 0; k < 4; ++k) {
                            uint2 u = M[qq * 256 + k * 64 + tid];
                            float val = __builtin_bit_cast(float, u.x);
                            INS4(val, (int)u.y, rv, ri);
                        }
                }
            }
            if (tid < 64) {
                size_t o = ((size_t)(bm + hf * 64 + tid) * NB + nb) * 4;
#pragma unroll
                for (int k = 0; k < 4; ++k)
                    part[o + k] =
                        make_uint2(__builtin_bit_cast(uint32_t, rv[k]), (uint32_t)ri[k]);
            }
        }
    }
}

// ---------------------------------------------------------------------------
// Deep fallbacks: f32-input GEMM + full-sim topk (tiny ws).
// ---------------------------------------------------------------------------
__global__ __launch_bounds__(256) void rnorm_kernel(const float* __restrict__ X,
                                                    float* __restrict__ r, int R) {
    int row = blockIdx.x * 4 + (threadIdx.x >> 6);
    if (row >= R) return;
    int lane = threadIdx.x & 63;
    const float* x = X + (size_t)row * D_DIM;
    float s = 0.f;
#pragma unroll
    for (int t = 0; t < 2; ++t) {
        float4 v = *(const float4*)(x + (t * 64 + lane) * 4);
        s += v.x * v.x + v.y * v.y + v.z * v.z + v.w * v.w;
    }
#pragma unroll
    for (int off = 32; off; off >>= 1) s += __shfl_xor(s, off);
    if (lane == 0) r[row] = 1.0f / fmaxf(sqrtf(s), 1e-12f);
}

__global__ __launch_bounds__(256, 2) void gemm_bf16_sim(const float* __restrict__ Z,
        const float* __restrict__ Pm, const float* __restrict__ rz,
        const float* __restrict__ rp, float* __restrict__ sim, int Pn) {
    __shared__ uint4 As16[1024];
    __shared__ uint4 Bs16[1024];
    int bi = blockIdx.x;
    int nb = bi % (Pn / 128);
    int mb = bi / (Pn / 128);
    const int bm = mb * 128, bn = nb * 128;
    const int tid = threadIdx.x;
    const int srow = tid >> 1;
    const int half = tid & 1;
    const float* aP = Z  + (size_t)(bm + srow) * D_DIM + half * 32;
    const float* bP = Pm + (size_t)(bn + srow) * D_DIM + half * 32;
    const int lane = tid & 63;
    const int wid = tid >> 6;
    const int wr = wid >> 1, wc = wid & 1;
    const int ln15 = lane & 15, hi = lane >> 4;
    f32x4 acc[4][4] = {};
    float4 f[8], g[8];
#pragma unroll
    for (int q = 0; q < 8; ++q) {
        f[q] = *(const float4*)(aP + q * 4);
        g[q] = *(const float4*)(bP + q * 4);
    }
#pragma unroll 1
    for (int s = 0; s < 8; ++s) {
#pragma unroll
        for (int q8 = 0; q8 < 4; ++q8) {
            uint4 wa, wb;
            wa.x = pk_bf16(f[2*q8].x,   f[2*q8].y);
            wa.y = pk_bf16(f[2*q8].z,   f[2*q8].w);
            wa.z = pk_bf16(f[2*q8+1].x, f[2*q8+1].y);
            wa.w = pk_bf16(f[2*q8+1].z, f[2*q8+1].w);
            wb.x = pk_bf16(g[2*q8].x,   g[2*q8].y);
            wb.y = pk_bf16(g[2*q8].z,   g[2*q8].w);
            wb.z = pk_bf16(g[2*q8+1].x, g[2*q8+1].y);
            wb.w = pk_bf16(g[2*q8+1].z, g[2*q8+1].w);
            int colByte = half * 64 + q8 * 16;
            int idx = srow * 8 + ((colByte ^ ((srow & 7) << 4)) >> 4);
            As16[idx] = wa;
            Bs16[idx] = wb;
        }
        __syncthreads();
        if (s < 7) {
            int k0 = (s + 1) * 64;
#pragma unroll
            for (int q = 0; q < 8; ++q) {
                f[q] = *(const float4*)(aP + k0 + q * 4);
                g[q] = *(const float4*)(bP + k0 + q * 4);
            }
        }
#pragma unroll
        for (int kk = 0; kk < 2; ++kk) {
            bf16x8 av[4], bv[4];
            const int cb = kk * 64 + hi * 16;
#pragma unroll
            for (int t = 0; t < 4; ++t) {
                int arow = wr * 64 + t * 16 + ln15;
                av[t] = __builtin_bit_cast(bf16x8,
                        As16[arow * 8 + ((cb ^ ((arow & 7) << 4)) >> 4)]);
                int brow = wc * 64 + t * 16 + ln15;
                bv[t] = __builtin_bit_cast(bf16x8,
                        Bs16[brow * 8 + ((cb ^ ((brow & 7) << 4)) >> 4)]);
            }
#pragma unroll
            for (int i = 0; i < 4; ++i)
#pragma unroll
                for (int j = 0; j < 4; ++j)
                    acc[i][j] = __builtin_amdgcn_mfma_f32_16x16x32_bf16(
                        av[i], bv[j], acc[i][j], 0, 0, 0);
        }
        __syncthreads();
    }
    float rpv[4];
#pragma unroll
    for (int j = 0; j < 4; ++j) rpv[j] = rp[bn + wc * 64 + j * 16 + ln15];
#pragma unroll
    for (int i = 0; i < 4; ++i) {
#pragma unroll
        for (int rr = 0; rr < 4; ++rr) {
            int row = bm + wr * 64 + i * 16 + hi * 4 + rr;
            float rzv = rz[row];
#pragma unroll
            for (int j = 0; j < 4; ++j) {
                int col = bn + wc * 64 + j * 16 + ln15;
                sim[(size_t)row * Pn + col] = acc[i][j][rr] * rzv * rpv[j];
            }
        }
    }
}

__global__ __launch_bounds__(256) void topk_refine(const float* __restrict__ sim,
        const float* __restrict__ Z, const float* __restrict__ Pm,
        const float* __restrict__ rz, const float* __restrict__ rp,
        float* __restrict__ oidx, float* __restrict__ oval, int Pn) {
    int row = blockIdx.x * 4 + (threadIdx.x >> 6);
    int lane = threadIdx.x & 63;
    const float* rptr = sim + (size_t)row * Pn;

    float v[8]; int ix[8];
#pragma unroll
    for (int j = 0; j < 8; ++j) { v[j] = -FLT_MAX; ix[j] = -1; }

    const int iters = Pn >> 8;
    for (int t = 0; t < iters; ++t) {
        int base = t * 256 + lane * 4;
        float4 q = *(const float4*)(rptr + base);
        float vals[4] = {q.x, q.y, q.z, q.w};
#pragma unroll
        for (int e = 0; e < 4; ++e) {
            float val = vals[e];
            if (val > v[7]) {
                int idx = base + e;
                int pos = 7;
#pragma unroll
                for (int j = 6; j >= 0; --j) {
                    if (val > v[j]) { v[j+1] = v[j]; ix[j+1] = ix[j]; pos = j; }
                }
                v[pos] = val; ix[pos] = idx;
            }
        }
    }

    int cand[8];
#pragma unroll
    for (int k = 0; k < 8; ++k) {
        float bv = v[0]; int bi2 = ix[0];
#pragma unroll
        for (int off = 32; off; off >>= 1) {
            float ov = __shfl_xor(bv, off);
            int oi = __shfl_xor(bi2, off);
            if (ov > bv || (ov == bv && oi >= 0 && (unsigned)oi < (unsigned)bi2)) {
                bv = ov; bi2 = oi;
            }
        }
        cand[k] = bi2;
        if (bi2 == ix[0]) {
#pragma unroll
            for (int j = 0; j < 7; ++j) { v[j] = v[j+1]; ix[j] = ix[j+1]; }
            v[7] = -FLT_MAX; ix[7] = -1;
        }
    }

    float zv[8];
    const float* zrow = Z + (size_t)row * D_DIM + lane * 8;
#pragma unroll
    for (int j = 0; j < 8; ++j) zv[j] = zrow[j];
    float rzv = rz[row];

    float ex[8];
#pragma unroll
    for (int c = 0; c < 8; ++c) {
        int idx = cand[c];
        const float* prow = Pm + (size_t)idx * D_DIM + lane * 8;
        float s = 0.f;
#pragma unroll
        for (int j = 0; j < 8; ++j) s += zv[j] * prow[j];
#pragma unroll
        for (int off = 32; off; off >>= 1) s += __shfl_xor(s, off);
        ex[c] = s * rzv * rp[idx];
    }

    bool used[8] = {};
#pragma unroll
    for (int k = 0; k < 3; ++k) {
        float bv = -FLT_MAX; int bi2 = Pn; int bc = 0;
#pragma unroll
        for (int c = 0; c < 8; ++c) {
            if (!used[c] && (ex[c] > bv || (ex[c] == bv && cand[c] < bi2))) {
                bv = ex[c]; bi2 = cand[c]; bc = c;
            }
        }
        used[bc] = true;
        if (lane == 0) {
            oidx[(size_t)row * 3 + k] = (float)bi2;
            oval[(size_t)row * 3 + k] = bv;
        }
    }
}

extern "C" void kernel_launch(void* const* d_in, const int* in_sizes, int n_in,
                              void* d_out, int out_size, void* d_ws, size_t ws_size,
                              hipStream_t stream) {
    const float* Z  = (const float*)d_in[0];   // [B, 512]
    const float* Pm = (const float*)d_in[1];   // [P, 512]
    const int B  = in_sizes[0] / D_DIM;        // 8192
    const int Pn = in_sizes[1] / D_DIM;        // 32768

    float* sim  = (float*)d_out;
    float* oidx = sim + (size_t)B * Pn;
    float* oval = oidx + (size_t)B * 3;

    float* rz = (float*)d_ws;
    float* rp = rz + B;
    unsigned short* Zb = (unsigned short*)(rp + Pn);
    unsigned short* Pb = Zb + (size_t)B * D_DIM;
    uint2* part = (uint2*)(Pb + (size_t)Pn * D_DIM);

    const size_t need_bf16 = (size_t)(B + Pn) * 4 + (size_t)(B + Pn) * D_DIM * 2;
    const size_t need256 = need_bf16 + (size_t)B * (Pn >> 8) * 4 * sizeof(uint2);
    const size_t need128 = need_bf16 + (size_t)B * (Pn >> 7) * 4 * sizeof(uint2);

    bool big = false;
    if ((B & 255) == 0 && (Pn & 255) == 0 && ws_size >= need256) {
        big = (hipFuncSetAttribute((const void*)gemm256_fused,
                   hipFuncAttributeMaxDynamicSharedMemorySize,
                   131072) == hipSuccess);
    }

    if (big) {
        convert_norm_kernel<<<B / 4, 256, 0, stream>>>(Z, Zb, rz, B);
        convert_norm_kernel<<<Pn / 4, 256, 0, stream>>>(Pm, Pb, rp, Pn);
        gemm256_fused<<<(B / 256) * (Pn / 256), 512, 131072, stream>>>(
            Zb, Pb, sim, part, Pn);
        topk_reduce<<<B / 4, 256, 0, stream>>>(part, Z, Pm, rz, rp,
                                               oidx, oval, Pn, Pn >> 8);
    } else if (ws_size >= need128) {
        convert_norm_kernel<<<B / 4, 256, 0, stream>>>(Z, Zb, rz, B);
        convert_norm_kernel<<<Pn / 4, 256, 0, stream>>>(Pm, Pb, rp, Pn);
        gemm_lds_bf16<true><<<(B / 128) * (Pn / 128), 256, 0, stream>>>(
            Zb, Pb, sim, part, Pn);
        topk_reduce<<<B / 4, 256, 0, stream>>>(part, Z, Pm, rz, rp,
                                               oidx, oval, Pn, Pn >> 7);
    } else if (ws_size >= need_bf16) {
        convert_norm_kernel<<<B / 4, 256, 0, stream>>>(Z, Zb, rz, B);
        convert_norm_kernel<<<Pn / 4, 256, 0, stream>>>(Pm, Pb, rp, Pn);
        gemm_lds_bf16<false><<<(B / 128) * (Pn / 128), 256, 0, stream>>>(
            Zb, Pb, sim, nullptr, Pn);
        topk_refine<<<B / 4, 256, 0, stream>>>(sim, Z, Pm, rz, rp, oidx, oval, Pn);
    } else {
        rnorm_kernel<<<B / 4, 256, 0, stream>>>(Z, rz, B);
        rnorm_kernel<<<Pn / 4, 256, 0, stream>>>(Pm, rp, Pn);
        gemm_bf16_sim<<<(B / 128) * (Pn / 128), 256, 0, stream>>>(
            Z, Pm, rz, rp, sim, Pn);
        topk_refine<<<B / 4, 256, 0, stream>>>(sim, Z, Pm, rz, rp, oidx, oval, Pn);
    }
}